// Round 1
// baseline (235.584 us; speedup 1.0000x reference)
//
#include <hip/hip_runtime.h>

// Problem constants (from reference) — ALL TENSORS ARE FLOAT32.
#define NPP   64
#define NRR   8
#define NKK   500
#define HDIM  256
#define NHEAD 8
#define VDIM  8
#define HD    32
#define BTOT  512   // NPP*NRR

// ---- fast transcendentals (hardware v_exp_f32 / v_rcp_f32) ----
__device__ __forceinline__ float fast_tanh(float x) {
  const float e = __expf(2.f * x);
  return 1.f - 2.f * __builtin_amdgcn_rcpf(e + 1.f);
}
__device__ __forceinline__ float fast_sig(float x) {
  return __builtin_amdgcn_rcpf(1.f + __expf(-x));
}

// ===========================================================================
// Kernel 1: LSTM cell GEMM, 32x32 tile, 64 threads, 4x4 per thread via
// ds_read_b128 (row pad 40 floats = 160 B keeps 16B alignment + 0 conflicts).
// Block (0,0) probes mask dtype into ws flag.
// ===========================================================================
__global__ __launch_bounds__(64) void k_lstm4(
    const float* __restrict__ query, const float* __restrict__ state1,
    const float* __restrict__ state2,
    const float* __restrict__ W_ih, const float* __restrict__ W_hh,
    const float* __restrict__ b_ih, const float* __restrict__ b_hh,
    const unsigned char* __restrict__ maskb, int* __restrict__ flagp,
    float* __restrict__ out_h, float* __restrict__ out_c)
{
  __shared__ float Wt[32][40];   // [k][gate-row]
  __shared__ float At[32][40];   // [k][batch-col]
  __shared__ float gt[32][40];   // gate exchange

  const int t  = threadIdx.x;    // 64
  const int hb = blockIdx.x;     // 32 tiles of 8 h (x4 gate parts)
  const int bb = blockIdx.y;     // 16 batch tiles of 32

  if (flagp != nullptr && hb == 0 && bb == 0) {
    __shared__ int f;
    if (t == 0) f = 0;
    __syncthreads();
    int any = 0;
    for (int j = t; j < 2048; j += 64) any |= maskb[2 * j + 1];
    if (any) atomicOr(&f, 1);
    __syncthreads();
    if (t == 0) *flagp = f;
  }

  const int tr = t >> 3, tc = t & 7;          // 8x8 thread grid, 4x4 each
  const int srow = t >> 1, sseg = (t & 1) * 16;
  const int wgrow = (srow >> 3) * HDIM + hb * 8 + (srow & 7);
  const int agrow = bb * 32 + srow;

  float acc[4][4];
#pragma unroll
  for (int i = 0; i < 4; ++i)
#pragma unroll
    for (int j = 0; j < 4; ++j) acc[i][j] = 0.f;

  for (int k0 = 0; k0 < 512; k0 += 32) {
    __syncthreads();
    {
      const float* wsrc = (k0 < 256) ? (W_ih + (size_t)wgrow * HDIM + k0)
                                     : (W_hh + (size_t)wgrow * HDIM + (k0 - 256));
      const float* asrc = (k0 < 256) ? (query  + (size_t)agrow * HDIM + k0)
                                     : (state1 + (size_t)agrow * HDIM + (k0 - 256));
#pragma unroll
      for (int j = 0; j < 4; ++j) {
        const float4 wv = *reinterpret_cast<const float4*>(wsrc + sseg + 4 * j);
        const float4 av = *reinterpret_cast<const float4*>(asrc + sseg + 4 * j);
        const int kk = sseg + 4 * j;
        Wt[kk + 0][srow] = wv.x; Wt[kk + 1][srow] = wv.y;
        Wt[kk + 2][srow] = wv.z; Wt[kk + 3][srow] = wv.w;
        At[kk + 0][srow] = av.x; At[kk + 1][srow] = av.y;
        At[kk + 2][srow] = av.z; At[kk + 3][srow] = av.w;
      }
    }
    __syncthreads();
#pragma unroll 8
    for (int kk = 0; kk < 32; ++kk) {
      const float4 wv = *reinterpret_cast<const float4*>(&Wt[kk][tr * 4]);
      const float4 av = *reinterpret_cast<const float4*>(&At[kk][tc * 4]);
      const float w[4] = {wv.x, wv.y, wv.z, wv.w};
      const float a[4] = {av.x, av.y, av.z, av.w};
#pragma unroll
      for (int i = 0; i < 4; ++i)
#pragma unroll
        for (int j = 0; j < 4; ++j) acc[i][j] += w[i] * a[j];
    }
  }

#pragma unroll
  for (int i = 0; i < 4; ++i) {
    float4 v;
    v.x = acc[i][0]; v.y = acc[i][1]; v.z = acc[i][2]; v.w = acc[i][3];
    *reinterpret_cast<float4*>(&gt[tr * 4 + i][tc * 4]) = v;
  }
  __syncthreads();

#pragma unroll
  for (int it = 0; it < 4; ++it) {
    const int cell = t + 64 * it;       // 256 cells = 8 h x 32 b
    const int b = cell & 31, h = cell >> 5;
    const int gh = hb * 8 + h;
    const int gb = bb * 32 + b;
    const float bi = b_ih[0 * HDIM + gh] + b_hh[0 * HDIM + gh];
    const float bf = b_ih[1 * HDIM + gh] + b_hh[1 * HDIM + gh];
    const float bg = b_ih[2 * HDIM + gh] + b_hh[2 * HDIM + gh];
    const float bo = b_ih[3 * HDIM + gh] + b_hh[3 * HDIM + gh];
    const float iv = fast_sig (gt[ 0 + h][b] + bi);
    const float fv = fast_sig (gt[ 8 + h][b] + bf);
    const float gv = fast_tanh(gt[16 + h][b] + bg);
    const float ov = fast_sig (gt[24 + h][b] + bo);
    const size_t off = (size_t)gb * HDIM + gh;
    const float c = fv * state2[off] + iv * gv;
    out_c[off] = c;
    out_h[off] = ov * fast_tanh(c);
  }
}

// ===========================================================================
// Kernel 2: small GEMM C[512][256] = scale * A[512][256] @ B(256x256).
// B element addressing: B[k][ct*32+cc] = Bbase[hstride*ct + k*ldb + cc]
//   - Q-proj: B = nn_Q [head][h][d]  -> hstride=8192, ldb=32
//   - qm    : B = nn_O [h][h']       -> hstride=32,   ldb=256
// 32x32 tile / 64 threads / 4x4 per thread, grid (8 coltiles, 16 rowtiles).
// ===========================================================================
__global__ __launch_bounds__(64) void k_gemm256(
    const float* __restrict__ A, const float* __restrict__ B,
    float* __restrict__ C, int hstride, int ldb, float scale)
{
  __shared__ float At[32][40];   // [k][row]
  __shared__ float Bt[32][40];   // [k][col]
  const int t  = threadIdx.x;
  const int ct = blockIdx.x;     // 8
  const int rt = blockIdx.y;     // 16
  const int tr = t >> 3, tc = t & 7;
  const int srow = t >> 1, sseg = (t & 1) * 16;

  const float* Asrc = A + ((size_t)(rt * 32 + srow)) * HDIM + sseg;
  const float* Bsrc = B + (size_t)hstride * ct + (size_t)srow * ldb + sseg;

  float acc[4][4];
#pragma unroll
  for (int i = 0; i < 4; ++i)
#pragma unroll
    for (int j = 0; j < 4; ++j) acc[i][j] = 0.f;

  for (int k0 = 0; k0 < 256; k0 += 32) {
    __syncthreads();
#pragma unroll
    for (int j = 0; j < 4; ++j) {
      const float4 av = *reinterpret_cast<const float4*>(Asrc + k0 + 4 * j);
      const int kk = sseg + 4 * j;
      At[kk + 0][srow] = av.x; At[kk + 1][srow] = av.y;
      At[kk + 2][srow] = av.z; At[kk + 3][srow] = av.w;
      const float4 bv = *reinterpret_cast<const float4*>(
          Bsrc + (size_t)k0 * ldb + 4 * j);
      *reinterpret_cast<float4*>(&Bt[srow][sseg + 4 * j]) = bv;
    }
    __syncthreads();
#pragma unroll 8
    for (int kk = 0; kk < 32; ++kk) {
      const float4 av = *reinterpret_cast<const float4*>(&At[kk][tr * 4]);
      const float4 bv = *reinterpret_cast<const float4*>(&Bt[kk][tc * 4]);
      const float a[4] = {av.x, av.y, av.z, av.w};
      const float b[4] = {bv.x, bv.y, bv.z, bv.w};
#pragma unroll
      for (int i = 0; i < 4; ++i)
#pragma unroll
        for (int j = 0; j < 4; ++j) acc[i][j] += a[i] * b[j];
    }
  }

  const int orow = rt * 32 + tr * 4;
  const int ocol = ct * 32 + tc * 4;
#pragma unroll
  for (int i = 0; i < 4; ++i) {
    float4 v;
    v.x = acc[i][0] * scale; v.y = acc[i][1] * scale;
    v.z = acc[i][2] * scale; v.w = acc[i][3] * scale;
    *reinterpret_cast<float4*>(C + (size_t)(orow + i) * HDIM + ocol) = v;
  }
}

// ===========================================================================
// Kernel 3: attention per (p, head), 512 threads.  K/V prefetched to regs at
// entry; Q read from global with wave-uniform addresses (scalarizes);
// Sb padded to 512 cols with -inf (softmax -> exact 0, so PV is unguarded).
// Writes x[p][r][a*32+d] to ws; qm GEMM runs separately.
// ===========================================================================
__global__ __launch_bounds__(512, 4) void k_attn7(
    const float* __restrict__ Kt, const float* __restrict__ Vt,
    const float* __restrict__ Qg, const void* __restrict__ maskp,
    const int* __restrict__ flagp, float* __restrict__ xg)
{
  const int p = blockIdx.x >> 3;
  const int a = blockIdx.x & 7;
  const int t = threadIdx.x;
  const int wave = t >> 6, lane = t & 63;

  __shared__ float Sb[NRR][512];        // 16 KB (cols 500..511 = -inf pad)
  __shared__ float pb[16][NRR][HD];     // 16 KB PV partials

  // ---------- K prefetch (one k per thread) ------------------------------
  const int kc = (t < NKK) ? t : (NKK - 1);
  const float4* kp4 = reinterpret_cast<const float4*>(
      Kt + (((size_t)a * NPP + p) * NKK + kc) * HD);
  float4 kreg[8];
#pragma unroll
  for (int j = 0; j < 8; ++j) kreg[j] = kp4[j];

  // ---------- V prefetch (32 k-slots x 1 dim per thread) -----------------
  const int dpv = t & 31, kb = t >> 5;  // kb in [0,16)
  const float* vb = Vt + (((size_t)a * NPP + p) * NKK + (size_t)kb * 32) * HD + dpv;
  float vreg[32];
#pragma unroll
  for (int j = 0; j < 32; ++j)
    vreg[j] = (kb * 32 + j < NKK) ? vb[(size_t)j * HD] : 0.f;

  // ---------- mask -------------------------------------------------------
  const int flag = *flagp;
  float maskv[NRR];
  {
    const unsigned char* mb = (const unsigned char*)maskp;
    const int* mi = (const int*)maskp;
#pragma unroll
    for (int r = 0; r < NRR; ++r) {
      const size_t mo = (size_t)(p * NRR + r) * NKK + kc;
      const bool mk = flag ? (mb[mo] != 0) : (mi[mo] != 0);
      maskv[r] = mk ? -INFINITY : 0.f;
    }
  }

  // ---------- scores: Q is wave-uniform -> s_load broadcast --------------
#pragma unroll
  for (int r = 0; r < NRR; ++r) {
    const float4* q4 = reinterpret_cast<const float4*>(
        Qg + ((size_t)(p * NRR + r)) * HDIM + a * HD);
    float s = 0.f;
#pragma unroll
    for (int j = 0; j < 8; ++j) {
      const float4 q = q4[j], k4 = kreg[j];
      s += q.x * k4.x + q.y * k4.y + q.z * k4.z + q.w * k4.w;
    }
    Sb[r][t] = (t < NKK) ? (s + maskv[r]) : -INFINITY;
  }
  __syncthreads();

  // ---------- softmax: wave w -> rollout w (8 waves = 8 rollouts) --------
  {
    const int r = wave;
    float lv[8], m = -INFINITY;
#pragma unroll
    for (int i = 0; i < 8; ++i) {
      lv[i] = Sb[r][lane + 64 * i];
      m = fmaxf(m, lv[i]);
    }
#pragma unroll
    for (int off = 32; off > 0; off >>= 1) m = fmaxf(m, __shfl_xor(m, off, 64));
    float ssum = 0.f;
#pragma unroll
    for (int i = 0; i < 8; ++i) {
      lv[i] = __expf(lv[i] - m);
      ssum += lv[i];
    }
#pragma unroll
    for (int off = 32; off > 0; off >>= 1) ssum += __shfl_xor(ssum, off, 64);
    const float inv = 1.f / ssum;
#pragma unroll
    for (int i = 0; i < 8; ++i) Sb[r][lane + 64 * i] = lv[i] * inv;
  }
  __syncthreads();

  // ---------- PV from prefetched vreg; Sb reads are fp4 broadcasts -------
  {
    float acc[NRR];
#pragma unroll
    for (int r = 0; r < NRR; ++r) acc[r] = 0.f;
#pragma unroll
    for (int j4 = 0; j4 < 8; ++j4) {
      const float v0 = vreg[j4 * 4 + 0], v1 = vreg[j4 * 4 + 1];
      const float v2 = vreg[j4 * 4 + 2], v3 = vreg[j4 * 4 + 3];
#pragma unroll
      for (int r = 0; r < NRR; ++r) {
        const float4 s4 = *reinterpret_cast<const float4*>(
            &Sb[r][kb * 32 + j4 * 4]);
        acc[r] += s4.x * v0 + s4.y * v1 + s4.z * v2 + s4.w * v3;
      }
    }
#pragma unroll
    for (int r = 0; r < NRR; ++r) pb[kb][r][dpv] = acc[r];
  }
  __syncthreads();

  if (t < 256) {
    const int r = t >> 5, d = t & 31;
    float s = 0.f;
#pragma unroll
    for (int q = 0; q < 16; ++q) s += pb[q][r][d];
    xg[((size_t)(p * NRR + r)) * HDIM + a * HD + d] = s;
  }
}

// ===========================================================================
// Kernel 4: additive logits.  Grid 64 x 32.  Wave owns 4 k; lane owns 4 h.
// ALL operands (nn_A, qm+nn_B, nn_W) hoisted into registers — zero LDS.
// ===========================================================================
__global__ __launch_bounds__(256) void k_logits5(
    const float* __restrict__ X, const float* __restrict__ varfeat,
    const float* __restrict__ nn_A, const float* __restrict__ nn_B,
    const float* __restrict__ nn_W, const float* __restrict__ qm,
    const int* __restrict__ flagp, const void* __restrict__ maskp,
    float* __restrict__ ls)
{
  const int p  = blockIdx.x >> 5;
  const int kt = blockIdx.x & 31;
  const int t = threadIdx.x;
  const int wave = t >> 6, lane = t & 63;
  const int h0 = lane * 4;

  const unsigned char* mb = (const unsigned char*)maskp;
  const int* mi = (const int*)maskp;
  const int flag = *flagp;
  const bool mbyte = (flag != 0);

  const float4 w4 = *reinterpret_cast<const float4*>(nn_W + h0);
  const float4 b4 = *reinterpret_cast<const float4*>(nn_B + h0);
  float4 a4r[VDIM];
#pragma unroll
  for (int v = 0; v < VDIM; ++v)
    a4r[v] = *reinterpret_cast<const float4*>(nn_A + (size_t)v * HDIM + h0);
  float4 q4r[NRR];
#pragma unroll
  for (int r = 0; r < NRR; ++r) {
    const float4 q = *reinterpret_cast<const float4*>(
        qm + (size_t)(p * NRR + r) * HDIM + h0);
    q4r[r].x = q.x + b4.x; q4r[r].y = q.y + b4.y;
    q4r[r].z = q.z + b4.z; q4r[r].w = q.w + b4.w;
  }

  for (int kk = 0; kk < 4; ++kk) {
    const int k = kt * 16 + wave * 4 + kk;
    if (k >= NKK) break;   // wave-uniform

    const float4 x4 = *reinterpret_cast<const float4*>(
        X + ((size_t)p * NKK + k) * HDIM + h0);
    float base0 = x4.x, base1 = x4.y, base2 = x4.z, base3 = x4.w;
#pragma unroll
    for (int v = 0; v < VDIM; ++v) {
      const float vv = varfeat[((size_t)p * VDIM + v) * NKK + k];
      base0 += vv * a4r[v].x; base1 += vv * a4r[v].y;
      base2 += vv * a4r[v].z; base3 += vv * a4r[v].w;
    }

    float acc[NRR];
#pragma unroll
    for (int r = 0; r < NRR; ++r) {
      acc[r] = fast_tanh(base0 + q4r[r].x) * w4.x
             + fast_tanh(base1 + q4r[r].y) * w4.y
             + fast_tanh(base2 + q4r[r].z) * w4.z
             + fast_tanh(base3 + q4r[r].w) * w4.w;
    }

    // multi-value wave reduction: 8 sums across 64 lanes
    float v4[4];
    {
      float sw[8];
#pragma unroll
      for (int j = 0; j < 8; ++j) sw[j] = __shfl_xor(acc[j], 32, 64);
      const bool hi = (lane & 32) != 0;
#pragma unroll
      for (int j = 0; j < 4; ++j)
        v4[j] = hi ? (acc[j + 4] + sw[j + 4]) : (acc[j] + sw[j]);
    }
    float v2[2];
    {
      float sw[4];
#pragma unroll
      for (int j = 0; j < 4; ++j) sw[j] = __shfl_xor(v4[j], 16, 64);
      const bool hi = (lane & 16) != 0;
      v2[0] = hi ? (v4[2] + sw[2]) : (v4[0] + sw[0]);
      v2[1] = hi ? (v4[3] + sw[3]) : (v4[1] + sw[1]);
    }
    float w;
    {
      const float s0 = __shfl_xor(v2[0], 8, 64);
      const float s1 = __shfl_xor(v2[1], 8, 64);
      w = ((lane & 8) != 0) ? (v2[1] + s1) : (v2[0] + s0);
    }
    w += __shfl_xor(w, 4, 64);
    w += __shfl_xor(w, 2, 64);
    w += __shfl_xor(w, 1, 64);

    if ((lane & 7) == 0) {
      const int r = lane >> 3;
      const size_t mrow = (size_t)(p * NRR + r) * NKK + k;
      const bool mk = mbyte ? (mb[mrow] != 0) : (mi[mrow] != 0);
      ls[mrow] = mk ? -INFINITY : fast_tanh(w) * 10.0f;
    }
  }
}

// ===========================================================================
// Kernel 5: choose.  One wave per batch row.
// ===========================================================================
__global__ __launch_bounds__(64) void k_choose(
    const float* __restrict__ ls, float* __restrict__ out_p)
{
  const int b = blockIdx.x;
  const int lane = threadIdx.x;
  float m = -INFINITY;
  float lv[8];
  int n = 0;
  for (int k = lane; k < NKK; k += 64, ++n) {
    lv[n] = ls[(size_t)b * NKK + k];
    m = fmaxf(m, lv[n]);
  }
#pragma unroll
  for (int off = 32; off > 0; off >>= 1) m = fmaxf(m, __shfl_xor(m, off, 64));
  float s = 0.f;
  for (int i = 0; i < n; ++i) s += __expf(lv[i] - m);
#pragma unroll
  for (int off = 32; off > 0; off >>= 1) s += __shfl_xor(s, off, 64);
  if (lane == 0) out_p[b] = -logf(s);
}

// ===========================================================================
// Fallback (ws too small): round-3 fused kernel — known-correct.
// ===========================================================================
__global__ __launch_bounds__(256) void k_fused(
    const float* __restrict__ X, const float* __restrict__ Kt,
    const float* __restrict__ Vt, const float* __restrict__ varfeat,
    const void* __restrict__ maskp,
    const float* __restrict__ nn_Q, const float* __restrict__ nn_O,
    const float* __restrict__ nn_A, const float* __restrict__ nn_B,
    const float* __restrict__ nn_W,
    const float* __restrict__ out_h, float* __restrict__ out_p)
{
  const int p = blockIdx.x >> 3;
  const int r = blockIdx.x & 7;
  const int t = threadIdx.x;
  const int wave = t >> 6, lane = t & 63;

  __shared__ float hs[HDIM];
  __shared__ float Qs[NHEAD][HD];
  __shared__ float Sb[NHEAD][NKK];
  __shared__ float xs[HDIM];
  __shared__ float qs[HDIM];
  __shared__ float As2[HDIM][VDIM];
  __shared__ float Ws[HDIM];
  __shared__ float lsb[NKK];
  __shared__ int   mask_any;

  const unsigned char* mb = (const unsigned char*)maskp;
  if (t == 0) mask_any = 0;
  __syncthreads();
  {
    int any = 0;
    for (int j = t; j < 2048; j += 256) any |= mb[2 * j + 1];
    if (any) atomicOr(&mask_any, 1);
  }
  for (int idx = t; idx < VDIM * HDIM; idx += 256)
    As2[idx & 255][idx >> 8] = nn_A[idx];
  Ws[t] = nn_W[t];
  hs[t] = out_h[(size_t)(p * NRR + r) * HDIM + t];
  __syncthreads();
  const bool mbyte = (mask_any != 0);
  const int* mi = (const int*)maskp;
  const size_t mrow = (size_t)(p * NRR + r) * NKK;
  {
    const int a = t >> 5, d = t & 31;
    const float* nq = nn_Q + (size_t)a * HDIM * HD + d;
    float acc = 0.f;
    for (int h = 0; h < HDIM; ++h) acc += hs[h] * nq[(size_t)h * HD];
    Qs[a][d] = acc * 0.17677669529663687f;
  }
  __syncthreads();
  for (int k = t; k < NKK; k += 256) {
    const bool mk = mbyte ? (mb[mrow + k] != 0) : (mi[mrow + k] != 0);
#pragma unroll
    for (int a = 0; a < NHEAD; ++a) {
      const float4* kr4 = reinterpret_cast<const float4*>(
          Kt + (((size_t)a * NPP + p) * NKK + k) * HD);
      float s = 0.f;
#pragma unroll
      for (int d4 = 0; d4 < HD / 4; ++d4) {
        const float4 u = kr4[d4];
        s += Qs[a][4 * d4] * u.x + Qs[a][4 * d4 + 1] * u.y
           + Qs[a][4 * d4 + 2] * u.z + Qs[a][4 * d4 + 3] * u.w;
      }
      Sb[a][k] = mk ? -INFINITY : s;
    }
  }
  __syncthreads();
  for (int aa = 0; aa < 2; ++aa) {
    const int a = wave * 2 + aa;
    float m = -INFINITY;
    for (int k = lane; k < NKK; k += 64) m = fmaxf(m, Sb[a][k]);
#pragma unroll
    for (int off = 32; off > 0; off >>= 1) m = fmaxf(m, __shfl_xor(m, off, 64));
    float ssum = 0.f;
    for (int k = lane; k < NKK; k += 64) {
      const float e = expf(Sb[a][k] - m);
      Sb[a][k] = e; ssum += e;
    }
#pragma unroll
    for (int off = 32; off > 0; off >>= 1) ssum += __shfl_xor(ssum, off, 64);
    const float inv = 1.f / ssum;
    for (int k = lane; k < NKK; k += 64) Sb[a][k] *= inv;
  }
  __syncthreads();
  {
    const int a = t >> 5, d = t & 31;
    const float* vb = Vt + ((size_t)a * NPP + p) * NKK * HD + d;
    float acc = 0.f;
    for (int k = 0; k < NKK; ++k) acc += Sb[a][k] * vb[(size_t)k * HD];
    xs[a * HD + d] = acc;
  }
  __syncthreads();
  {
    float acc = 0.f;
    for (int i = 0; i < HDIM; ++i) acc += xs[i] * nn_O[(size_t)i * HDIM + t];
    qs[t] = acc + nn_B[t];
  }
  __syncthreads();
  for (int k = t; k < NKK; k += 256) {
    float vfv[VDIM];
#pragma unroll
    for (int v = 0; v < VDIM; ++v)
      vfv[v] = varfeat[((size_t)p * VDIM + v) * NKK + k];
    const float4* xp4 = reinterpret_cast<const float4*>(
        X + ((size_t)p * NKK + k) * HDIM);
    float acc = 0.f;
    for (int h4 = 0; h4 < HDIM / 4; ++h4) {
      const float4 ux = xp4[h4];
      const float xv[4] = {ux.x, ux.y, ux.z, ux.w};
#pragma unroll
      for (int j = 0; j < 4; ++j) {
        const int h = 4 * h4 + j;
        float base = xv[j] + qs[h];
        const float4 a0 = *reinterpret_cast<const float4*>(&As2[h][0]);
        const float4 a1 = *reinterpret_cast<const float4*>(&As2[h][4]);
        base += vfv[0] * a0.x + vfv[1] * a0.y + vfv[2] * a0.z + vfv[3] * a0.w
              + vfv[4] * a1.x + vfv[5] * a1.y + vfv[6] * a1.z + vfv[7] * a1.w;
        acc += tanhf(base) * Ws[h];
      }
    }
    lsb[k] = acc;
  }
  __syncthreads();
  for (int k = t; k < NKK; k += 256) {
    const bool mk = mbyte ? (mb[mrow + k] != 0) : (mi[mrow + k] != 0);
    lsb[k] = mk ? -INFINITY : tanhf(lsb[k]) * 10.0f;
  }
  __syncthreads();
  if (wave == 0) {
    float m = -INFINITY;
    for (int k = lane; k < NKK; k += 64) m = fmaxf(m, lsb[k]);
#pragma unroll
    for (int off = 32; off > 0; off >>= 1) m = fmaxf(m, __shfl_xor(m, off, 64));
    float s = 0.f;
    for (int k = lane; k < NKK; k += 64) s += expf(lsb[k] - m);
#pragma unroll
    for (int off = 32; off > 0; off >>= 1) s += __shfl_xor(s, off, 64);
    if (lane == 0) out_p[p * NRR + r] = -logf(s);
  }
}

// ===========================================================================
extern "C" void kernel_launch(void* const* d_in, const int* in_sizes, int n_in,
                              void* d_out, int out_size, void* d_ws, size_t ws_size,
                              hipStream_t stream)
{
  const float* X       = (const float*)d_in[0];
  const float* Kt      = (const float*)d_in[1];
  const float* Vt      = (const float*)d_in[2];
  const float* query   = (const float*)d_in[3];
  const float* state1  = (const float*)d_in[4];
  const float* state2  = (const float*)d_in[5];
  const float* varfeat = (const float*)d_in[6];
  const void*  maskp   = d_in[7];
  const float* nn_Q    = (const float*)d_in[8];
  const float* nn_O    = (const float*)d_in[9];
  const float* nn_A    = (const float*)d_in[10];
  const float* nn_B    = (const float*)d_in[11];
  const float* nn_W    = (const float*)d_in[12];
  const float* W_ih    = (const float*)d_in[13];
  const float* W_hh    = (const float*)d_in[14];
  const float* b_ih    = (const float*)d_in[15];
  const float* b_hh    = (const float*)d_in[16];

  float* out   = (float*)d_out;
  float* out_h = out;
  float* out_c = out + (size_t)BTOT * HDIM;
  float* out_p = out + (size_t)2 * BTOT * HDIM;

  const size_t flag_bytes = 256;                       // aligned pad
  const size_t mat_bytes  = (size_t)BTOT * HDIM * 4;   // 512 KB each
  const size_t ls_bytes   = (size_t)BTOT * NKK * 4;    // 1 MB
  const size_t need = flag_bytes + 3 * mat_bytes + ls_bytes;  // ~2.62 MB

  if (ws_size >= need) {
    int*   flagp = (int*)d_ws;
    float* Qw  = (float*)((char*)d_ws + flag_bytes);
    float* xw  = (float*)((char*)d_ws + flag_bytes + mat_bytes);
    float* qmw = (float*)((char*)d_ws + flag_bytes + 2 * mat_bytes);
    float* lsw = (float*)((char*)d_ws + flag_bytes + 3 * mat_bytes);

    hipLaunchKernelGGL(k_lstm4, dim3(32, 16), dim3(64), 0, stream,
                       query, state1, state2, W_ih, W_hh, b_ih, b_hh,
                       (const unsigned char*)maskp, flagp, out_h, out_c);
    // Q[p*8+r][a*32+d] = (1/sqrt(32)) * h @ nn_Q
    hipLaunchKernelGGL(k_gemm256, dim3(8, 16), dim3(64), 0, stream,
                       out_h, nn_Q, Qw, HDIM * HD, HD, 0.17677669529663687f);
    hipLaunchKernelGGL(k_attn7, dim3(NPP * NHEAD), dim3(512), 0, stream,
                       Kt, Vt, Qw, maskp, flagp, xw);
    // qm = x @ nn_O
    hipLaunchKernelGGL(k_gemm256, dim3(8, 16), dim3(64), 0, stream,
                       xw, nn_O, qmw, HD, HDIM, 1.0f);
    hipLaunchKernelGGL(k_logits5, dim3(NPP * 32), dim3(256), 0, stream,
                       X, varfeat, nn_A, nn_B, nn_W, qmw, flagp, maskp, lsw);
    hipLaunchKernelGGL(k_choose, dim3(BTOT), dim3(64), 0, stream,
                       lsw, out_p);
  } else {
    hipLaunchKernelGGL(k_lstm4, dim3(32, 16), dim3(64), 0, stream,
                       query, state1, state2, W_ih, W_hh, b_ih, b_hh,
                       (const unsigned char*)maskp, nullptr, out_h, out_c);
    hipLaunchKernelGGL(k_fused, dim3(NPP * NRR), dim3(256), 0, stream,
                       X, Kt, Vt, varfeat, maskp,
                       nn_Q, nn_O, nn_A, nn_B, nn_W,
                       out_h, out_p);
  }
}

// Round 2
// 234.916 us; speedup vs baseline: 1.0028x; 1.0028x over previous
//
#include <hip/hip_runtime.h>

// Problem constants (from reference) — ALL TENSORS ARE FLOAT32.
#define NPP   64
#define NRR   8
#define NKK   500
#define HDIM  256
#define NHEAD 8
#define VDIM  8
#define HD    32
#define BTOT  512   // NPP*NRR

// ---- fast transcendentals (hardware v_exp_f32 / v_rcp_f32) ----
__device__ __forceinline__ float fast_tanh(float x) {
  const float e = __expf(2.f * x);
  return 1.f - 2.f * __builtin_amdgcn_rcpf(e + 1.f);
}
__device__ __forceinline__ float fast_sig(float x) {
  return __builtin_amdgcn_rcpf(1.f + __expf(-x));
}

// ===========================================================================
// Kernel 1: LSTM cell GEMM, 32x32 tile, 64 threads, 4x4 per thread via
// ds_read_b128 (row pad 40 floats keeps 16B alignment + no conflicts).
// Block (0,0) probes mask dtype into ws flag.
// ===========================================================================
__global__ __launch_bounds__(64) void k_lstm4(
    const float* __restrict__ query, const float* __restrict__ state1,
    const float* __restrict__ state2,
    const float* __restrict__ W_ih, const float* __restrict__ W_hh,
    const float* __restrict__ b_ih, const float* __restrict__ b_hh,
    const unsigned char* __restrict__ maskb, int* __restrict__ flagp,
    float* __restrict__ out_h, float* __restrict__ out_c)
{
  __shared__ float Wt[32][40];   // [k][gate-row]
  __shared__ float At[32][40];   // [k][batch-col]
  __shared__ float gt[32][40];   // gate exchange

  const int t  = threadIdx.x;    // 64
  const int hb = blockIdx.x;     // 32 tiles of 8 h (x4 gate parts)
  const int bb = blockIdx.y;     // 16 batch tiles of 32

  if (flagp != nullptr && hb == 0 && bb == 0) {
    __shared__ int f;
    if (t == 0) f = 0;
    __syncthreads();
    int any = 0;
    for (int j = t; j < 2048; j += 64) any |= maskb[2 * j + 1];
    if (any) atomicOr(&f, 1);
    __syncthreads();
    if (t == 0) *flagp = f;
  }

  const int tr = t >> 3, tc = t & 7;          // 8x8 thread grid, 4x4 each
  const int srow = t >> 1, sseg = (t & 1) * 16;
  const int wgrow = (srow >> 3) * HDIM + hb * 8 + (srow & 7);
  const int agrow = bb * 32 + srow;

  float acc[4][4];
#pragma unroll
  for (int i = 0; i < 4; ++i)
#pragma unroll
    for (int j = 0; j < 4; ++j) acc[i][j] = 0.f;

  for (int k0 = 0; k0 < 512; k0 += 32) {
    __syncthreads();
    {
      const float* wsrc = (k0 < 256) ? (W_ih + (size_t)wgrow * HDIM + k0)
                                     : (W_hh + (size_t)wgrow * HDIM + (k0 - 256));
      const float* asrc = (k0 < 256) ? (query  + (size_t)agrow * HDIM + k0)
                                     : (state1 + (size_t)agrow * HDIM + (k0 - 256));
#pragma unroll
      for (int j = 0; j < 4; ++j) {
        const float4 wv = *reinterpret_cast<const float4*>(wsrc + sseg + 4 * j);
        const float4 av = *reinterpret_cast<const float4*>(asrc + sseg + 4 * j);
        const int kk = sseg + 4 * j;
        Wt[kk + 0][srow] = wv.x; Wt[kk + 1][srow] = wv.y;
        Wt[kk + 2][srow] = wv.z; Wt[kk + 3][srow] = wv.w;
        At[kk + 0][srow] = av.x; At[kk + 1][srow] = av.y;
        At[kk + 2][srow] = av.z; At[kk + 3][srow] = av.w;
      }
    }
    __syncthreads();
#pragma unroll 8
    for (int kk = 0; kk < 32; ++kk) {
      const float4 wv = *reinterpret_cast<const float4*>(&Wt[kk][tr * 4]);
      const float4 av = *reinterpret_cast<const float4*>(&At[kk][tc * 4]);
      const float w[4] = {wv.x, wv.y, wv.z, wv.w};
      const float a[4] = {av.x, av.y, av.z, av.w};
#pragma unroll
      for (int i = 0; i < 4; ++i)
#pragma unroll
        for (int j = 0; j < 4; ++j) acc[i][j] += w[i] * a[j];
    }
  }

#pragma unroll
  for (int i = 0; i < 4; ++i) {
    float4 v;
    v.x = acc[i][0]; v.y = acc[i][1]; v.z = acc[i][2]; v.w = acc[i][3];
    *reinterpret_cast<float4*>(&gt[tr * 4 + i][tc * 4]) = v;
  }
  __syncthreads();

#pragma unroll
  for (int it = 0; it < 4; ++it) {
    const int cell = t + 64 * it;       // 256 cells = 8 h x 32 b
    const int b = cell & 31, h = cell >> 5;
    const int gh = hb * 8 + h;
    const int gb = bb * 32 + b;
    const float bi = b_ih[0 * HDIM + gh] + b_hh[0 * HDIM + gh];
    const float bf = b_ih[1 * HDIM + gh] + b_hh[1 * HDIM + gh];
    const float bg = b_ih[2 * HDIM + gh] + b_hh[2 * HDIM + gh];
    const float bo = b_ih[3 * HDIM + gh] + b_hh[3 * HDIM + gh];
    const float iv = fast_sig (gt[ 0 + h][b] + bi);
    const float fv = fast_sig (gt[ 8 + h][b] + bf);
    const float gv = fast_tanh(gt[16 + h][b] + bg);
    const float ov = fast_sig (gt[24 + h][b] + bo);
    const size_t off = (size_t)gb * HDIM + gh;
    const float c = fv * state2[off] + iv * gv;
    out_c[off] = c;
    out_h[off] = ov * fast_tanh(c);
  }
}

// ===========================================================================
// Kernel 2: attention per (p, head), 512 threads, FULLY FUSED:
//   Q-proj (8-way K-split per wave, coalesced 1KB nn_Q loads, shuffle-reduce)
//   -> scores (K prefetched to regs at entry; Qs read as LDS b128 broadcasts)
//   -> softmax (Sb padded to 512 with -inf -> exact 0, PV unguarded)
//   -> PV (V prefetched to regs) -> O-proj partial into per-head qm slab.
// ===========================================================================
__global__ __launch_bounds__(512, 4) void k_attn8(
    const float* __restrict__ Kt, const float* __restrict__ Vt,
    const float* __restrict__ nn_Q, const float* __restrict__ nn_O,
    const void* __restrict__ maskp, const int* __restrict__ flagp,
    const float* __restrict__ out_h, float* __restrict__ qm_slabs)
{
  const int p = blockIdx.x >> 3;
  const int a = blockIdx.x & 7;
  const int t = threadIdx.x;
  const int wave = t >> 6, lane = t & 63;

  __shared__ float hs[NRR][HDIM];       // 8 KB
  __shared__ float Qs[NRR][36];         // 1.1 KB (rows 144 B, 16B-aligned)
  __shared__ float Sb[NRR][512];        // 16 KB (cols 500..511 = -inf pad)
  __shared__ float pb[16][NRR][HD];     // 16 KB PV partials
  __shared__ float xs[NRR][36];         // 1.1 KB

  // ---------- h stage load (512 x float4 = full 8x256) -------------------
  const float4 hv = reinterpret_cast<const float4*>(
      out_h + (size_t)p * NRR * HDIM)[t];

  // ---------- flag + K / V / mask prefetch (regs; stay in flight) --------
  const int flag = *flagp;

  const int kc = (t < NKK) ? t : (NKK - 1);
  const float4* kp4 = reinterpret_cast<const float4*>(
      Kt + (((size_t)a * NPP + p) * NKK + kc) * HD);
  float4 kreg[8];
#pragma unroll
  for (int j = 0; j < 8; ++j) kreg[j] = kp4[j];

  const int dpv = t & 31, kb = t >> 5;  // kb in [0,16)
  const float* vb = Vt + (((size_t)a * NPP + p) * NKK + (size_t)kb * 32) * HD + dpv;
  float vreg[32];
#pragma unroll
  for (int j = 0; j < 32; ++j)
    vreg[j] = (kb * 32 + j < NKK) ? vb[(size_t)j * HD] : 0.f;

  float maskv[NRR];
  {
    const unsigned char* mb = (const unsigned char*)maskp;
    const int* mi = (const int*)maskp;
#pragma unroll
    for (int r = 0; r < NRR; ++r) {
      const size_t mo = (size_t)(p * NRR + r) * NKK + kc;
      const bool mk = flag ? (mb[mo] != 0) : (mi[mo] != 0);
      maskv[r] = mk ? -INFINITY : 0.f;
    }
  }

  reinterpret_cast<float4*>(&hs[0][0])[t] = hv;
  __syncthreads();

  // ---------- Q-proj: wave r; lane = (d4, kslice); K split 8-way ---------
  {
    const int r = wave, d4 = lane >> 3, ks = lane & 7;
    const float* qb = nn_Q + ((size_t)a * HDIM + ks * 32) * HD + d4 * 4;
    float qx = 0.f, qy = 0.f, qz = 0.f, qw = 0.f;
#pragma unroll
    for (int h = 0; h < 32; ++h) {
      const float hval = hs[r][ks * 32 + h];
      const float4 wv = *reinterpret_cast<const float4*>(qb + (size_t)h * HD);
      qx += hval * wv.x; qy += hval * wv.y;
      qz += hval * wv.z; qw += hval * wv.w;
    }
#pragma unroll
    for (int off = 1; off < 8; off <<= 1) {
      qx += __shfl_xor(qx, off, 64);
      qy += __shfl_xor(qy, off, 64);
      qz += __shfl_xor(qz, off, 64);
      qw += __shfl_xor(qw, off, 64);
    }
    if (ks == 0) {
      const float sc = 0.17677669529663687f;   // 1/sqrt(32)
      Qs[r][d4 * 4 + 0] = qx * sc; Qs[r][d4 * 4 + 1] = qy * sc;
      Qs[r][d4 * 4 + 2] = qz * sc; Qs[r][d4 * 4 + 3] = qw * sc;
    }
  }
  __syncthreads();

  // ---------- scores from prefetched kreg; Qs broadcast b128 reads -------
#pragma unroll
  for (int r = 0; r < NRR; ++r) {
    float s = 0.f;
#pragma unroll
    for (int j = 0; j < 8; ++j) {
      const float4 q = *reinterpret_cast<const float4*>(&Qs[r][j * 4]);
      const float4 k4 = kreg[j];
      s += q.x * k4.x + q.y * k4.y + q.z * k4.z + q.w * k4.w;
    }
    Sb[r][t] = (t < NKK) ? (s + maskv[r]) : -INFINITY;
  }
  __syncthreads();

  // ---------- softmax: wave w -> rollout w -------------------------------
  {
    const int r = wave;
    float lv[8], m = -INFINITY;
#pragma unroll
    for (int i = 0; i < 8; ++i) {
      lv[i] = Sb[r][lane + 64 * i];
      m = fmaxf(m, lv[i]);
    }
#pragma unroll
    for (int off = 32; off > 0; off >>= 1) m = fmaxf(m, __shfl_xor(m, off, 64));
    float ssum = 0.f;
#pragma unroll
    for (int i = 0; i < 8; ++i) {
      lv[i] = __expf(lv[i] - m);
      ssum += lv[i];
    }
#pragma unroll
    for (int off = 32; off > 0; off >>= 1) ssum += __shfl_xor(ssum, off, 64);
    const float inv = 1.f / ssum;
#pragma unroll
    for (int i = 0; i < 8; ++i) Sb[r][lane + 64 * i] = lv[i] * inv;
  }
  __syncthreads();

  // ---------- PV from prefetched vreg; Sb reads are b128 broadcasts ------
  {
    float acc[NRR];
#pragma unroll
    for (int r = 0; r < NRR; ++r) acc[r] = 0.f;
#pragma unroll
    for (int j4 = 0; j4 < 8; ++j4) {
      const float v0 = vreg[j4 * 4 + 0], v1 = vreg[j4 * 4 + 1];
      const float v2 = vreg[j4 * 4 + 2], v3 = vreg[j4 * 4 + 3];
#pragma unroll
      for (int r = 0; r < NRR; ++r) {
        const float4 s4 = *reinterpret_cast<const float4*>(
            &Sb[r][kb * 32 + j4 * 4]);
        acc[r] += s4.x * v0 + s4.y * v1 + s4.z * v2 + s4.w * v3;
      }
    }
#pragma unroll
    for (int r = 0; r < NRR; ++r) pb[kb][r][dpv] = acc[r];
  }
  __syncthreads();

  if (t < 256) {
    const int r = t >> 5, d = t & 31;
    float s = 0.f;
#pragma unroll
    for (int q = 0; q < 16; ++q) s += pb[q][r][d];
    xs[r][d] = s;
  }
  __syncthreads();

  // ---------- O-proj partial -> per-head slab ----------------------------
  {
    const int j = t & 255, rr = t >> 8;   // rr: r-group {0..3} or {4..7}
    float a0 = 0.f, a1 = 0.f, a2 = 0.f, a3 = 0.f;
#pragma unroll
    for (int d4 = 0; d4 < 8; ++d4) {
      const float4 x0 = *reinterpret_cast<const float4*>(&xs[rr * 4 + 0][d4 * 4]);
      const float4 x1 = *reinterpret_cast<const float4*>(&xs[rr * 4 + 1][d4 * 4]);
      const float4 x2 = *reinterpret_cast<const float4*>(&xs[rr * 4 + 2][d4 * 4]);
      const float4 x3 = *reinterpret_cast<const float4*>(&xs[rr * 4 + 3][d4 * 4]);
      const float c0[4] = {x0.x, x0.y, x0.z, x0.w};
      const float c1[4] = {x1.x, x1.y, x1.z, x1.w};
      const float c2[4] = {x2.x, x2.y, x2.z, x2.w};
      const float c3[4] = {x3.x, x3.y, x3.z, x3.w};
#pragma unroll
      for (int dd = 0; dd < 4; ++dd) {
        const float w = nn_O[((size_t)(a * HD + d4 * 4 + dd)) * HDIM + j];
        a0 += c0[dd] * w; a1 += c1[dd] * w;
        a2 += c2[dd] * w; a3 += c3[dd] * w;
      }
    }
    float* slab = qm_slabs + (size_t)a * BTOT * HDIM;
    slab[(size_t)(p * NRR + rr * 4 + 0) * HDIM + j] = a0;
    slab[(size_t)(p * NRR + rr * 4 + 1) * HDIM + j] = a1;
    slab[(size_t)(p * NRR + rr * 4 + 2) * HDIM + j] = a2;
    slab[(size_t)(p * NRR + rr * 4 + 3) * HDIM + j] = a3;
  }
}

// ===========================================================================
// Kernel 3: additive logits + per-(row, kt) softmax partials.
// Grid 64 x 32.  Wave owns 4 k; lane owns 4 h.  Slab-sum staged in LDS once,
// hoisted to registers.  Emits (max_l, sum exp(l-10)) — no ls materialized.
// ===========================================================================
__global__ __launch_bounds__(256) void k_logits6(
    const float* __restrict__ X, const float* __restrict__ varfeat,
    const float* __restrict__ nn_A, const float* __restrict__ nn_B,
    const float* __restrict__ nn_W, const float* __restrict__ qm_slabs,
    const int* __restrict__ flagp, const void* __restrict__ maskp,
    float* __restrict__ pmax, float* __restrict__ psum)
{
  const int p  = blockIdx.x >> 5;
  const int kt = blockIdx.x & 31;
  const int t = threadIdx.x;
  const int wave = t >> 6, lane = t & 63;
  const int h0 = lane * 4;

  __shared__ float qb[NRR][260];        // summed slabs + nn_B
  __shared__ float red[4][NRR][2];      // per-wave (max, sum) partials

  const unsigned char* mb = (const unsigned char*)maskp;
  const int* mi = (const int*)maskp;
  const int flag = *flagp;
  const bool mbyte = (flag != 0);

  // ---- stage qb = sum_a slab[a] + nn_B (512 float4 slots, 2 per thread) --
  for (int s = t; s < 512; s += 256) {
    const int r = s >> 6, h4 = s & 63;
    const float4 bv = *reinterpret_cast<const float4*>(nn_B + h4 * 4);
    float qx = bv.x, qy = bv.y, qz = bv.z, qw = bv.w;
#pragma unroll
    for (int a = 0; a < NHEAD; ++a) {
      const float4 q = *reinterpret_cast<const float4*>(
          qm_slabs + (size_t)a * BTOT * HDIM +
          (size_t)(p * NRR + r) * HDIM + h4 * 4);
      qx += q.x; qy += q.y; qz += q.z; qw += q.w;
    }
    qb[r][h4 * 4 + 0] = qx; qb[r][h4 * 4 + 1] = qy;
    qb[r][h4 * 4 + 2] = qz; qb[r][h4 * 4 + 3] = qw;
  }
  __syncthreads();

  // ---- hoist loop-invariants to registers --------------------------------
  const float4 w4 = *reinterpret_cast<const float4*>(nn_W + h0);
  float4 a4r[VDIM];
#pragma unroll
  for (int v = 0; v < VDIM; ++v)
    a4r[v] = *reinterpret_cast<const float4*>(nn_A + (size_t)v * HDIM + h0);
  float4 q4r[NRR];
#pragma unroll
  for (int r = 0; r < NRR; ++r)
    q4r[r] = *reinterpret_cast<const float4*>(&qb[r][h0]);

  float rmax = -INFINITY, rsum = 0.f;    // valid at lanes with (lane&7)==0

  for (int kk = 0; kk < 4; ++kk) {
    const int k = kt * 16 + wave * 4 + kk;
    if (k >= NKK) break;   // wave-uniform

    const float4 x4 = *reinterpret_cast<const float4*>(
        X + ((size_t)p * NKK + k) * HDIM + h0);
    float base0 = x4.x, base1 = x4.y, base2 = x4.z, base3 = x4.w;
#pragma unroll
    for (int v = 0; v < VDIM; ++v) {
      const float vv = varfeat[((size_t)p * VDIM + v) * NKK + k];
      base0 += vv * a4r[v].x; base1 += vv * a4r[v].y;
      base2 += vv * a4r[v].z; base3 += vv * a4r[v].w;
    }

    float acc[NRR];
#pragma unroll
    for (int r = 0; r < NRR; ++r) {
      acc[r] = fast_tanh(base0 + q4r[r].x) * w4.x
             + fast_tanh(base1 + q4r[r].y) * w4.y
             + fast_tanh(base2 + q4r[r].z) * w4.z
             + fast_tanh(base3 + q4r[r].w) * w4.w;
    }

    // multi-value wave reduction: 8 sums across 64 lanes
    float v4[4];
    {
      float sw[8];
#pragma unroll
      for (int j = 0; j < 8; ++j) sw[j] = __shfl_xor(acc[j], 32, 64);
      const bool hi = (lane & 32) != 0;
#pragma unroll
      for (int j = 0; j < 4; ++j)
        v4[j] = hi ? (acc[j + 4] + sw[j + 4]) : (acc[j] + sw[j]);
    }
    float v2[2];
    {
      float sw[4];
#pragma unroll
      for (int j = 0; j < 4; ++j) sw[j] = __shfl_xor(v4[j], 16, 64);
      const bool hi = (lane & 16) != 0;
      v2[0] = hi ? (v4[2] + sw[2]) : (v4[0] + sw[0]);
      v2[1] = hi ? (v4[3] + sw[3]) : (v4[1] + sw[1]);
    }
    float w;
    {
      const float s0 = __shfl_xor(v2[0], 8, 64);
      const float s1 = __shfl_xor(v2[1], 8, 64);
      w = ((lane & 8) != 0) ? (v2[1] + s1) : (v2[0] + s0);
    }
    w += __shfl_xor(w, 4, 64);
    w += __shfl_xor(w, 2, 64);
    w += __shfl_xor(w, 1, 64);

    if ((lane & 7) == 0) {
      const int r = lane >> 3;
      const size_t mrow = (size_t)(p * NRR + r) * NKK + k;
      const bool mk = mbyte ? (mb[mrow] != 0) : (mi[mrow] != 0);
      const float l = mk ? -INFINITY : fast_tanh(w) * 10.0f;
      rmax = fmaxf(rmax, l);
      rsum += __expf(l - 10.f);          // exp(-inf) = 0 for masked
    }
  }

  if ((lane & 7) == 0) {
    red[wave][lane >> 3][0] = rmax;
    red[wave][lane >> 3][1] = rsum;
  }
  __syncthreads();
  if (t < NRR) {
    float m = red[0][t][0], s = red[0][t][1];
#pragma unroll
    for (int w = 1; w < 4; ++w) {
      m = fmaxf(m, red[w][t][0]);
      s += red[w][t][1];
    }
    pmax[(size_t)(p * NRR + t) * 32 + kt] = m;
    psum[(size_t)(p * NRR + t) * 32 + kt] = s;
  }
}

// ===========================================================================
// Kernel 4: choose.  One wave per batch row; reduce the 32 kt-partials.
// chosen_p = m - LSE = m - 10 - log(sum exp(l-10)).
// ===========================================================================
__global__ __launch_bounds__(64) void k_choose2(
    const float* __restrict__ pmax, const float* __restrict__ psum,
    float* __restrict__ out_p)
{
  const int b = blockIdx.x;
  const int lane = threadIdx.x;
  float m = (lane < 32) ? pmax[(size_t)b * 32 + lane] : -INFINITY;
  float s = (lane < 32) ? psum[(size_t)b * 32 + lane] : 0.f;
#pragma unroll
  for (int off = 16; off > 0; off >>= 1) {
    m = fmaxf(m, __shfl_xor(m, off, 64));
    s += __shfl_xor(s, off, 64);
  }
  if (lane == 0) out_p[b] = m - 10.f - logf(s);
}

// ===========================================================================
// Fallback (ws too small): round-3 fused kernel — known-correct.
// ===========================================================================
__global__ __launch_bounds__(256) void k_fused(
    const float* __restrict__ X, const float* __restrict__ Kt,
    const float* __restrict__ Vt, const float* __restrict__ varfeat,
    const void* __restrict__ maskp,
    const float* __restrict__ nn_Q, const float* __restrict__ nn_O,
    const float* __restrict__ nn_A, const float* __restrict__ nn_B,
    const float* __restrict__ nn_W,
    const float* __restrict__ out_h, float* __restrict__ out_p)
{
  const int p = blockIdx.x >> 3;
  const int r = blockIdx.x & 7;
  const int t = threadIdx.x;
  const int wave = t >> 6, lane = t & 63;

  __shared__ float hs[HDIM];
  __shared__ float Qs[NHEAD][HD];
  __shared__ float Sb[NHEAD][NKK];
  __shared__ float xs[HDIM];
  __shared__ float qs[HDIM];
  __shared__ float As2[HDIM][VDIM];
  __shared__ float Ws[HDIM];
  __shared__ float lsb[NKK];
  __shared__ int   mask_any;

  const unsigned char* mb = (const unsigned char*)maskp;
  if (t == 0) mask_any = 0;
  __syncthreads();
  {
    int any = 0;
    for (int j = t; j < 2048; j += 256) any |= mb[2 * j + 1];
    if (any) atomicOr(&mask_any, 1);
  }
  for (int idx = t; idx < VDIM * HDIM; idx += 256)
    As2[idx & 255][idx >> 8] = nn_A[idx];
  Ws[t] = nn_W[t];
  hs[t] = out_h[(size_t)(p * NRR + r) * HDIM + t];
  __syncthreads();
  const bool mbyte = (mask_any != 0);
  const int* mi = (const int*)maskp;
  const size_t mrow = (size_t)(p * NRR + r) * NKK;
  {
    const int a = t >> 5, d = t & 31;
    const float* nq = nn_Q + (size_t)a * HDIM * HD + d;
    float acc = 0.f;
    for (int h = 0; h < HDIM; ++h) acc += hs[h] * nq[(size_t)h * HD];
    Qs[a][d] = acc * 0.17677669529663687f;
  }
  __syncthreads();
  for (int k = t; k < NKK; k += 256) {
    const bool mk = mbyte ? (mb[mrow + k] != 0) : (mi[mrow + k] != 0);
#pragma unroll
    for (int a = 0; a < NHEAD; ++a) {
      const float4* kr4 = reinterpret_cast<const float4*>(
          Kt + (((size_t)a * NPP + p) * NKK + k) * HD);
      float s = 0.f;
#pragma unroll
      for (int d4 = 0; d4 < HD / 4; ++d4) {
        const float4 u = kr4[d4];
        s += Qs[a][4 * d4] * u.x + Qs[a][4 * d4 + 1] * u.y
           + Qs[a][4 * d4 + 2] * u.z + Qs[a][4 * d4 + 3] * u.w;
      }
      Sb[a][k] = mk ? -INFINITY : s;
    }
  }
  __syncthreads();
  for (int aa = 0; aa < 2; ++aa) {
    const int a = wave * 2 + aa;
    float m = -INFINITY;
    for (int k = lane; k < NKK; k += 64) m = fmaxf(m, Sb[a][k]);
#pragma unroll
    for (int off = 32; off > 0; off >>= 1) m = fmaxf(m, __shfl_xor(m, off, 64));
    float ssum = 0.f;
    for (int k = lane; k < NKK; k += 64) {
      const float e = expf(Sb[a][k] - m);
      Sb[a][k] = e; ssum += e;
    }
#pragma unroll
    for (int off = 32; off > 0; off >>= 1) ssum += __shfl_xor(ssum, off, 64);
    const float inv = 1.f / ssum;
    for (int k = lane; k < NKK; k += 64) Sb[a][k] *= inv;
  }
  __syncthreads();
  {
    const int a = t >> 5, d = t & 31;
    const float* vb = Vt + ((size_t)a * NPP + p) * NKK * HD + d;
    float acc = 0.f;
    for (int k = 0; k < NKK; ++k) acc += Sb[a][k] * vb[(size_t)k * HD];
    xs[a * HD + d] = acc;
  }
  __syncthreads();
  {
    float acc = 0.f;
    for (int i = 0; i < HDIM; ++i) acc += xs[i] * nn_O[(size_t)i * HDIM + t];
    qs[t] = acc + nn_B[t];
  }
  __syncthreads();
  for (int k = t; k < NKK; k += 256) {
    float vfv[VDIM];
#pragma unroll
    for (int v = 0; v < VDIM; ++v)
      vfv[v] = varfeat[((size_t)p * VDIM + v) * NKK + k];
    const float4* xp4 = reinterpret_cast<const float4*>(
        X + ((size_t)p * NKK + k) * HDIM);
    float acc = 0.f;
    for (int h4 = 0; h4 < HDIM / 4; ++h4) {
      const float4 ux = xp4[h4];
      const float xv[4] = {ux.x, ux.y, ux.z, ux.w};
#pragma unroll
      for (int j = 0; j < 4; ++j) {
        const int h = 4 * h4 + j;
        float base = xv[j] + qs[h];
        const float4 a0 = *reinterpret_cast<const float4*>(&As2[h][0]);
        const float4 a1 = *reinterpret_cast<const float4*>(&As2[h][4]);
        base += vfv[0] * a0.x + vfv[1] * a0.y + vfv[2] * a0.z + vfv[3] * a0.w
              + vfv[4] * a1.x + vfv[5] * a1.y + vfv[6] * a1.z + vfv[7] * a1.w;
        acc += tanhf(base) * Ws[h];
      }
    }
    lsb[k] = acc;
  }
  __syncthreads();
  for (int k = t; k < NKK; k += 256) {
    const bool mk = mbyte ? (mb[mrow + k] != 0) : (mi[mrow + k] != 0);
    lsb[k] = mk ? -INFINITY : tanhf(lsb[k]) * 10.0f;
  }
  __syncthreads();
  if (wave == 0) {
    float m = -INFINITY;
    for (int k = lane; k < NKK; k += 64) m = fmaxf(m, lsb[k]);
#pragma unroll
    for (int off = 32; off > 0; off >>= 1) m = fmaxf(m, __shfl_xor(m, off, 64));
    float s = 0.f;
    for (int k = lane; k < NKK; k += 64) s += expf(lsb[k] - m);
#pragma unroll
    for (int off = 32; off > 0; off >>= 1) s += __shfl_xor(s, off, 64);
    if (lane == 0) out_p[p * NRR + r] = -logf(s);
  }
}

// ===========================================================================
extern "C" void kernel_launch(void* const* d_in, const int* in_sizes, int n_in,
                              void* d_out, int out_size, void* d_ws, size_t ws_size,
                              hipStream_t stream)
{
  const float* X       = (const float*)d_in[0];
  const float* Kt      = (const float*)d_in[1];
  const float* Vt      = (const float*)d_in[2];
  const float* query   = (const float*)d_in[3];
  const float* state1  = (const float*)d_in[4];
  const float* state2  = (const float*)d_in[5];
  const float* varfeat = (const float*)d_in[6];
  const void*  maskp   = d_in[7];
  const float* nn_Q    = (const float*)d_in[8];
  const float* nn_O    = (const float*)d_in[9];
  const float* nn_A    = (const float*)d_in[10];
  const float* nn_B    = (const float*)d_in[11];
  const float* nn_W    = (const float*)d_in[12];
  const float* W_ih    = (const float*)d_in[13];
  const float* W_hh    = (const float*)d_in[14];
  const float* b_ih    = (const float*)d_in[15];
  const float* b_hh    = (const float*)d_in[16];

  float* out   = (float*)d_out;
  float* out_h = out;
  float* out_c = out + (size_t)BTOT * HDIM;
  float* out_p = out + (size_t)2 * BTOT * HDIM;

  const size_t flag_bytes = 256;                               // aligned pad
  const size_t qm8_bytes  = (size_t)NHEAD * BTOT * HDIM * 4;   // 4 MB
  const size_t part_bytes = (size_t)BTOT * 32 * 4;             // 64 KB each
  const size_t need = flag_bytes + qm8_bytes + 2 * part_bytes; // ~4.2 MB

  if (ws_size >= need) {
    int*   flagp = (int*)d_ws;
    float* qmw  = (float*)((char*)d_ws + flag_bytes);
    float* pmax = (float*)((char*)d_ws + flag_bytes + qm8_bytes);
    float* psum = (float*)((char*)d_ws + flag_bytes + qm8_bytes + part_bytes);

    hipLaunchKernelGGL(k_lstm4, dim3(32, 16), dim3(64), 0, stream,
                       query, state1, state2, W_ih, W_hh, b_ih, b_hh,
                       (const unsigned char*)maskp, flagp, out_h, out_c);
    hipLaunchKernelGGL(k_attn8, dim3(NPP * NHEAD), dim3(512), 0, stream,
                       Kt, Vt, nn_Q, nn_O, maskp, flagp, out_h, qmw);
    hipLaunchKernelGGL(k_logits6, dim3(NPP * 32), dim3(256), 0, stream,
                       X, varfeat, nn_A, nn_B, nn_W, qmw, flagp, maskp,
                       pmax, psum);
    hipLaunchKernelGGL(k_choose2, dim3(BTOT), dim3(64), 0, stream,
                       pmax, psum, out_p);
  } else {
    hipLaunchKernelGGL(k_lstm4, dim3(32, 16), dim3(64), 0, stream,
                       query, state1, state2, W_ih, W_hh, b_ih, b_hh,
                       (const unsigned char*)maskp, nullptr, out_h, out_c);
    hipLaunchKernelGGL(k_fused, dim3(NPP * NRR), dim3(256), 0, stream,
                       X, Kt, Vt, varfeat, maskp,
                       nn_Q, nn_O, nn_A, nn_B, nn_W,
                       out_h, out_p);
  }
}

// Round 3
// 232.126 us; speedup vs baseline: 1.0149x; 1.0120x over previous
//
#include <hip/hip_runtime.h>

// Problem constants (from reference) — ALL TENSORS ARE FLOAT32.
#define NPP   64
#define NRR   8
#define NKK   500
#define HDIM  256
#define NHEAD 8
#define VDIM  8
#define HD    32
#define BTOT  512   // NPP*NRR

// ---- fast transcendentals (hardware v_exp_f32 / v_rcp_f32) ----
__device__ __forceinline__ float fast_tanh(float x) {
  const float e = __expf(2.f * x);
  return 1.f - 2.f * __builtin_amdgcn_rcpf(e + 1.f);
}
__device__ __forceinline__ float fast_sig(float x) {
  return __builtin_amdgcn_rcpf(1.f + __expf(-x));
}

// ===========================================================================
// Kernel 1: LSTM cell, tiled GEMM, 32 gate-rows x 32 batch tiles, 256 thr
// (round-0 proven config).  Block (0,0) probes the mask dtype into ws flag.
// ===========================================================================
__global__ __launch_bounds__(256) void k_lstm3(
    const float* __restrict__ query, const float* __restrict__ state1,
    const float* __restrict__ state2,
    const float* __restrict__ W_ih, const float* __restrict__ W_hh,
    const float* __restrict__ b_ih, const float* __restrict__ b_hh,
    const unsigned char* __restrict__ maskb, int* __restrict__ flagp,
    float* __restrict__ out_h, float* __restrict__ out_c)
{
  __shared__ float Wt[32][33];
  __shared__ float At[32][33];
  __shared__ float gt[32][33];

  const int t  = threadIdx.x;
  const int hb = blockIdx.x;
  const int bb = blockIdx.y;

  if (flagp != nullptr && hb == 0 && bb == 0) {
    __shared__ int f;
    if (t == 0) f = 0;
    __syncthreads();
    int any = 0;
    for (int j = t; j < 2048; j += 256) any |= maskb[2 * j + 1];
    if (any) atomicOr(&f, 1);
    __syncthreads();
    if (t == 0) *flagp = f;
  }

  const int trow = t >> 4;
  const int tcol = t & 15;

  float acc00 = 0.f, acc01 = 0.f, acc10 = 0.f, acc11 = 0.f;

  const int wrow = t >> 3, wk4 = t & 7;
  const int wpart = wrow >> 3, whh = wrow & 7;
  const int wgrow = wpart * HDIM + hb * 8 + whh;
  const int agrow = bb * 32 + wrow;

  for (int k0 = 0; k0 < 512; k0 += 32) {
    __syncthreads();
    {
      const float* wsrc = (k0 < 256) ? (W_ih + (size_t)wgrow * HDIM + k0)
                                     : (W_hh + (size_t)wgrow * HDIM + (k0 - 256));
      const float4 wv = *reinterpret_cast<const float4*>(wsrc + wk4 * 4);
      Wt[wk4 * 4 + 0][wrow] = wv.x; Wt[wk4 * 4 + 1][wrow] = wv.y;
      Wt[wk4 * 4 + 2][wrow] = wv.z; Wt[wk4 * 4 + 3][wrow] = wv.w;

      const float* asrc = (k0 < 256) ? (query  + (size_t)agrow * HDIM + k0)
                                     : (state1 + (size_t)agrow * HDIM + (k0 - 256));
      const float4 av = *reinterpret_cast<const float4*>(asrc + wk4 * 4);
      At[wk4 * 4 + 0][wrow] = av.x; At[wk4 * 4 + 1][wrow] = av.y;
      At[wk4 * 4 + 2][wrow] = av.z; At[wk4 * 4 + 3][wrow] = av.w;
    }
    __syncthreads();

#pragma unroll 8
    for (int kk = 0; kk < 32; ++kk) {
      const float w0 = Wt[kk][trow], w1 = Wt[kk][trow + 16];
      const float a0 = At[kk][tcol], a1 = At[kk][tcol + 16];
      acc00 += w0 * a0; acc01 += w0 * a1;
      acc10 += w1 * a0; acc11 += w1 * a1;
    }
  }

  gt[trow][tcol] = acc00;      gt[trow][tcol + 16] = acc01;
  gt[trow + 16][tcol] = acc10; gt[trow + 16][tcol + 16] = acc11;
  __syncthreads();

  {
    const int h = t & 7, b = t >> 3;
    const int gh = hb * 8 + h;
    const int gb = bb * 32 + b;
    const float bi = b_ih[0 * HDIM + gh] + b_hh[0 * HDIM + gh];
    const float bf = b_ih[1 * HDIM + gh] + b_hh[1 * HDIM + gh];
    const float bg = b_ih[2 * HDIM + gh] + b_hh[2 * HDIM + gh];
    const float bo = b_ih[3 * HDIM + gh] + b_hh[3 * HDIM + gh];
    const float iv = fast_sig (gt[ 0 + h][b] + bi);
    const float fv = fast_sig (gt[ 8 + h][b] + bf);
    const float gv = fast_tanh(gt[16 + h][b] + bg);
    const float ov = fast_sig (gt[24 + h][b] + bo);
    const size_t off = (size_t)gb * HDIM + gh;
    const float c = fv * state2[off] + iv * gv;
    out_c[off] = c;
    out_h[off] = ov * fast_tanh(c);
  }
}

// ===========================================================================
// Kernel 2: attention per (p, head, rollout-half), 512 threads, 1024 blocks.
// Rollout-split doubles resident blocks (4/CU: LDS ~22 KB) and halves each
// block's serial phase chain.  Twins (same p,a) are 512 apart in blockIdx ->
// same XCD -> second K/V read can hit that XCD's L2.  No combine needed:
// softmax is per-rollout.
// ===========================================================================
__global__ __launch_bounds__(512, 4) void k_attn9(
    const float* __restrict__ Kt, const float* __restrict__ Vt,
    const float* __restrict__ nn_Q, const float* __restrict__ nn_O,
    const void* __restrict__ maskp, const int* __restrict__ flagp,
    const float* __restrict__ out_h, float* __restrict__ qm_slabs)
{
  const int bid  = blockIdx.x;
  const int half = bid >> 9;          // 0 / 1  (twins 512 apart: same XCD)
  const int pa   = bid & 511;
  const int p    = pa >> 3;
  const int a    = pa & 7;
  const int r0   = half * 4;          // global rollout base
  const int t    = threadIdx.x;
  const int wave = t >> 6, lane = t & 63;

  __shared__ float hs[4][HDIM];       // 4 KB
  __shared__ float Qp[2][4][36];      // 1.1 KB Q-proj h-half partials
  __shared__ float Qs[4][36];         // 0.6 KB
  __shared__ float Sb[4][512];        // 8 KB (cols 500..511 = -inf pad)
  __shared__ float pb[16][4][HD];     // 8 KB PV partials
  __shared__ float xs[4][36];         // 0.6 KB

  // ---------- h stage load (4 rows x 256 = 256 float4) -------------------
  float4 hv = make_float4(0.f, 0.f, 0.f, 0.f);
  if (t < 256)
    hv = reinterpret_cast<const float4*>(
        out_h + (size_t)(p * NRR + r0) * HDIM)[t];

  // ---------- flag + K / V / mask prefetch -------------------------------
  const int flag = *flagp;

  const int kc = (t < NKK) ? t : (NKK - 1);
  const float4* kp4 = reinterpret_cast<const float4*>(
      Kt + (((size_t)a * NPP + p) * NKK + kc) * HD);
  float4 kreg[8];
#pragma unroll
  for (int j = 0; j < 8; ++j) kreg[j] = kp4[j];

  const int dpv = t & 31, kb = t >> 5;  // kb in [0,16)
  const float* vb = Vt + (((size_t)a * NPP + p) * NKK + (size_t)kb * 32) * HD + dpv;
  float vreg[32];
#pragma unroll
  for (int j = 0; j < 32; ++j)
    vreg[j] = (kb * 32 + j < NKK) ? vb[(size_t)j * HD] : 0.f;

  float maskv[4];
  {
    const unsigned char* mb = (const unsigned char*)maskp;
    const int* mi = (const int*)maskp;
#pragma unroll
    for (int r = 0; r < 4; ++r) {
      const size_t mo = (size_t)(p * NRR + r0 + r) * NKK + kc;
      const bool mk = flag ? (mb[mo] != 0) : (mi[mo] != 0);
      maskv[r] = mk ? -INFINITY : 0.f;
    }
  }

  if (t < 256) reinterpret_cast<float4*>(&hs[0][0])[t] = hv;
  __syncthreads();

  // ---------- Q-proj: wave = (hh, rloc); lane = (d4, ks) -----------------
  {
    const int rloc = wave & 3, hh = wave >> 2;
    const int d4 = lane >> 3, ks = lane & 7;
    const int hbase = hh * 128 + ks * 16;
    const float* qb = nn_Q + ((size_t)a * HDIM + hbase) * HD + d4 * 4;
    float qx = 0.f, qy = 0.f, qz = 0.f, qw = 0.f;
#pragma unroll
    for (int h = 0; h < 16; ++h) {
      const float hval = hs[rloc][hbase + h];
      const float4 wv = *reinterpret_cast<const float4*>(qb + (size_t)h * HD);
      qx += hval * wv.x; qy += hval * wv.y;
      qz += hval * wv.z; qw += hval * wv.w;
    }
#pragma unroll
    for (int off = 1; off < 8; off <<= 1) {
      qx += __shfl_xor(qx, off, 64);
      qy += __shfl_xor(qy, off, 64);
      qz += __shfl_xor(qz, off, 64);
      qw += __shfl_xor(qw, off, 64);
    }
    if (ks == 0) {
      Qp[hh][rloc][d4 * 4 + 0] = qx; Qp[hh][rloc][d4 * 4 + 1] = qy;
      Qp[hh][rloc][d4 * 4 + 2] = qz; Qp[hh][rloc][d4 * 4 + 3] = qw;
    }
  }
  __syncthreads();
  if (t < 128) {
    const int rr = t >> 5, d = t & 31;
    Qs[rr][d] = (Qp[0][rr][d] + Qp[1][rr][d]) * 0.17677669529663687f;
  }
  __syncthreads();

  // ---------- scores from prefetched kreg; Qs broadcast b128 reads -------
#pragma unroll
  for (int r = 0; r < 4; ++r) {
    float s = 0.f;
#pragma unroll
    for (int j = 0; j < 8; ++j) {
      const float4 q = *reinterpret_cast<const float4*>(&Qs[r][j * 4]);
      const float4 k4 = kreg[j];
      s += q.x * k4.x + q.y * k4.y + q.z * k4.z + q.w * k4.w;
    }
    Sb[r][t] = (t < NKK) ? (s + maskv[r]) : -INFINITY;
  }
  __syncthreads();

  // ---------- softmax: wave w (<4) -> rollout w --------------------------
  if (wave < 4) {
    const int r = wave;
    float lv[8], m = -INFINITY;
#pragma unroll
    for (int i = 0; i < 8; ++i) {
      lv[i] = Sb[r][lane + 64 * i];
      m = fmaxf(m, lv[i]);
    }
#pragma unroll
    for (int off = 32; off > 0; off >>= 1) m = fmaxf(m, __shfl_xor(m, off, 64));
    float ssum = 0.f;
#pragma unroll
    for (int i = 0; i < 8; ++i) {
      lv[i] = __expf(lv[i] - m);
      ssum += lv[i];
    }
#pragma unroll
    for (int off = 32; off > 0; off >>= 1) ssum += __shfl_xor(ssum, off, 64);
    const float inv = 1.f / ssum;
#pragma unroll
    for (int i = 0; i < 8; ++i) Sb[r][lane + 64 * i] = lv[i] * inv;
  }
  __syncthreads();

  // ---------- PV from prefetched vreg; Sb reads are broadcasts -----------
  {
    float acc[4];
#pragma unroll
    for (int r = 0; r < 4; ++r) acc[r] = 0.f;
#pragma unroll
    for (int j4 = 0; j4 < 8; ++j4) {
      const float v0 = vreg[j4 * 4 + 0], v1 = vreg[j4 * 4 + 1];
      const float v2 = vreg[j4 * 4 + 2], v3 = vreg[j4 * 4 + 3];
#pragma unroll
      for (int r = 0; r < 4; ++r) {
        const float4 s4 = *reinterpret_cast<const float4*>(
            &Sb[r][kb * 32 + j4 * 4]);
        acc[r] += s4.x * v0 + s4.y * v1 + s4.z * v2 + s4.w * v3;
      }
    }
#pragma unroll
    for (int r = 0; r < 4; ++r) pb[kb][r][dpv] = acc[r];
  }
  __syncthreads();

  if (t < 128) {
    const int r = t >> 5, d = t & 31;
    float s = 0.f;
#pragma unroll
    for (int q = 0; q < 16; ++q) s += pb[q][r][d];
    xs[r][d] = s;
  }
  __syncthreads();

  // ---------- O-proj partial -> per-head slab (2 rows per thread) --------
  {
    const int j = t & 255, rr = t >> 8;   // rr in {0,1} -> local rows 2rr,2rr+1
    float a0 = 0.f, a1 = 0.f;
#pragma unroll
    for (int d4 = 0; d4 < 8; ++d4) {
      const float4 x0 = *reinterpret_cast<const float4*>(&xs[rr * 2 + 0][d4 * 4]);
      const float4 x1 = *reinterpret_cast<const float4*>(&xs[rr * 2 + 1][d4 * 4]);
      const float c0[4] = {x0.x, x0.y, x0.z, x0.w};
      const float c1[4] = {x1.x, x1.y, x1.z, x1.w};
#pragma unroll
      for (int dd = 0; dd < 4; ++dd) {
        const float w = nn_O[((size_t)(a * HD + d4 * 4 + dd)) * HDIM + j];
        a0 += c0[dd] * w; a1 += c1[dd] * w;
      }
    }
    float* slab = qm_slabs + (size_t)a * BTOT * HDIM;
    slab[(size_t)(p * NRR + r0 + rr * 2 + 0) * HDIM + j] = a0;
    slab[(size_t)(p * NRR + r0 + rr * 2 + 1) * HDIM + j] = a1;
  }
}

// ===========================================================================
// Kernel 3: additive logits + per-(row, kt) softmax partials.
// Grid 64 x 32.  Wave owns 4 k; lane owns 4 h.  Slab-sum staged in LDS once,
// hoisted to registers.  Emits (max_l, sum exp(l-10)) — no ls materialized.
// ===========================================================================
__global__ __launch_bounds__(256) void k_logits6(
    const float* __restrict__ X, const float* __restrict__ varfeat,
    const float* __restrict__ nn_A, const float* __restrict__ nn_B,
    const float* __restrict__ nn_W, const float* __restrict__ qm_slabs,
    const int* __restrict__ flagp, const void* __restrict__ maskp,
    float* __restrict__ pmax, float* __restrict__ psum)
{
  const int p  = blockIdx.x >> 5;
  const int kt = blockIdx.x & 31;
  const int t = threadIdx.x;
  const int wave = t >> 6, lane = t & 63;
  const int h0 = lane * 4;

  __shared__ float qb[NRR][260];        // summed slabs + nn_B
  __shared__ float red[4][NRR][2];      // per-wave (max, sum) partials

  const unsigned char* mb = (const unsigned char*)maskp;
  const int* mi = (const int*)maskp;
  const int flag = *flagp;
  const bool mbyte = (flag != 0);

  // ---- stage qb = sum_a slab[a] + nn_B (512 float4 slots, 2 per thread) --
  for (int s = t; s < 512; s += 256) {
    const int r = s >> 6, h4 = s & 63;
    const float4 bv = *reinterpret_cast<const float4*>(nn_B + h4 * 4);
    float qx = bv.x, qy = bv.y, qz = bv.z, qw = bv.w;
#pragma unroll
    for (int a = 0; a < NHEAD; ++a) {
      const float4 q = *reinterpret_cast<const float4*>(
          qm_slabs + (size_t)a * BTOT * HDIM +
          (size_t)(p * NRR + r) * HDIM + h4 * 4);
      qx += q.x; qy += q.y; qz += q.z; qw += q.w;
    }
    qb[r][h4 * 4 + 0] = qx; qb[r][h4 * 4 + 1] = qy;
    qb[r][h4 * 4 + 2] = qz; qb[r][h4 * 4 + 3] = qw;
  }
  __syncthreads();

  // ---- hoist loop-invariants to registers --------------------------------
  const float4 w4 = *reinterpret_cast<const float4*>(nn_W + h0);
  float4 a4r[VDIM];
#pragma unroll
  for (int v = 0; v < VDIM; ++v)
    a4r[v] = *reinterpret_cast<const float4*>(nn_A + (size_t)v * HDIM + h0);
  float4 q4r[NRR];
#pragma unroll
  for (int r = 0; r < NRR; ++r)
    q4r[r] = *reinterpret_cast<const float4*>(&qb[r][h0]);

  float rmax = -INFINITY, rsum = 0.f;    // valid at lanes with (lane&7)==0

  for (int kk = 0; kk < 4; ++kk) {
    const int k = kt * 16 + wave * 4 + kk;
    if (k >= NKK) break;   // wave-uniform

    const float4 x4 = *reinterpret_cast<const float4*>(
        X + ((size_t)p * NKK + k) * HDIM + h0);
    float base0 = x4.x, base1 = x4.y, base2 = x4.z, base3 = x4.w;
#pragma unroll
    for (int v = 0; v < VDIM; ++v) {
      const float vv = varfeat[((size_t)p * VDIM + v) * NKK + k];
      base0 += vv * a4r[v].x; base1 += vv * a4r[v].y;
      base2 += vv * a4r[v].z; base3 += vv * a4r[v].w;
    }

    float acc[NRR];
#pragma unroll
    for (int r = 0; r < NRR; ++r) {
      acc[r] = fast_tanh(base0 + q4r[r].x) * w4.x
             + fast_tanh(base1 + q4r[r].y) * w4.y
             + fast_tanh(base2 + q4r[r].z) * w4.z
             + fast_tanh(base3 + q4r[r].w) * w4.w;
    }

    // multi-value wave reduction: 8 sums across 64 lanes
    float v4[4];
    {
      float sw[8];
#pragma unroll
      for (int j = 0; j < 8; ++j) sw[j] = __shfl_xor(acc[j], 32, 64);
      const bool hi = (lane & 32) != 0;
#pragma unroll
      for (int j = 0; j < 4; ++j)
        v4[j] = hi ? (acc[j + 4] + sw[j + 4]) : (acc[j] + sw[j]);
    }
    float v2[2];
    {
      float sw[4];
#pragma unroll
      for (int j = 0; j < 4; ++j) sw[j] = __shfl_xor(v4[j], 16, 64);
      const bool hi = (lane & 16) != 0;
      v2[0] = hi ? (v4[2] + sw[2]) : (v4[0] + sw[0]);
      v2[1] = hi ? (v4[3] + sw[3]) : (v4[1] + sw[1]);
    }
    float w;
    {
      const float s0 = __shfl_xor(v2[0], 8, 64);
      const float s1 = __shfl_xor(v2[1], 8, 64);
      w = ((lane & 8) != 0) ? (v2[1] + s1) : (v2[0] + s0);
    }
    w += __shfl_xor(w, 4, 64);
    w += __shfl_xor(w, 2, 64);
    w += __shfl_xor(w, 1, 64);

    if ((lane & 7) == 0) {
      const int r = lane >> 3;
      const size_t mrow = (size_t)(p * NRR + r) * NKK + k;
      const bool mk = mbyte ? (mb[mrow] != 0) : (mi[mrow] != 0);
      const float l = mk ? -INFINITY : fast_tanh(w) * 10.0f;
      rmax = fmaxf(rmax, l);
      rsum += __expf(l - 10.f);          // exp(-inf) = 0 for masked
    }
  }

  if ((lane & 7) == 0) {
    red[wave][lane >> 3][0] = rmax;
    red[wave][lane >> 3][1] = rsum;
  }
  __syncthreads();
  if (t < NRR) {
    float m = red[0][t][0], s = red[0][t][1];
#pragma unroll
    for (int w = 1; w < 4; ++w) {
      m = fmaxf(m, red[w][t][0]);
      s += red[w][t][1];
    }
    pmax[(size_t)(p * NRR + t) * 32 + kt] = m;
    psum[(size_t)(p * NRR + t) * 32 + kt] = s;
  }
}

// ===========================================================================
// Kernel 4: choose.  One wave per batch row; reduce the 32 kt-partials.
// chosen_p = m - LSE = m - 10 - log(sum exp(l-10)).
// ===========================================================================
__global__ __launch_bounds__(64) void k_choose2(
    const float* __restrict__ pmax, const float* __restrict__ psum,
    float* __restrict__ out_p)
{
  const int b = blockIdx.x;
  const int lane = threadIdx.x;
  float m = (lane < 32) ? pmax[(size_t)b * 32 + lane] : -INFINITY;
  float s = (lane < 32) ? psum[(size_t)b * 32 + lane] : 0.f;
#pragma unroll
  for (int off = 16; off > 0; off >>= 1) {
    m = fmaxf(m, __shfl_xor(m, off, 64));
    s += __shfl_xor(s, off, 64);
  }
  if (lane == 0) out_p[b] = m - 10.f - logf(s);
}

// ===========================================================================
// Fallback (ws too small): round-3 fused kernel — known-correct.
// ===========================================================================
__global__ __launch_bounds__(256) void k_fused(
    const float* __restrict__ X, const float* __restrict__ Kt,
    const float* __restrict__ Vt, const float* __restrict__ varfeat,
    const void* __restrict__ maskp,
    const float* __restrict__ nn_Q, const float* __restrict__ nn_O,
    const float* __restrict__ nn_A, const float* __restrict__ nn_B,
    const float* __restrict__ nn_W,
    const float* __restrict__ out_h, float* __restrict__ out_p)
{
  const int p = blockIdx.x >> 3;
  const int r = blockIdx.x & 7;
  const int t = threadIdx.x;
  const int wave = t >> 6, lane = t & 63;

  __shared__ float hs[HDIM];
  __shared__ float Qs[NHEAD][HD];
  __shared__ float Sb[NHEAD][NKK];
  __shared__ float xs[HDIM];
  __shared__ float qs[HDIM];
  __shared__ float As2[HDIM][VDIM];
  __shared__ float Ws[HDIM];
  __shared__ float lsb[NKK];
  __shared__ int   mask_any;

  const unsigned char* mb = (const unsigned char*)maskp;
  if (t == 0) mask_any = 0;
  __syncthreads();
  {
    int any = 0;
    for (int j = t; j < 2048; j += 256) any |= mb[2 * j + 1];
    if (any) atomicOr(&mask_any, 1);
  }
  for (int idx = t; idx < VDIM * HDIM; idx += 256)
    As2[idx & 255][idx >> 8] = nn_A[idx];
  Ws[t] = nn_W[t];
  hs[t] = out_h[(size_t)(p * NRR + r) * HDIM + t];
  __syncthreads();
  const bool mbyte = (mask_any != 0);
  const int* mi = (const int*)maskp;
  const size_t mrow = (size_t)(p * NRR + r) * NKK;
  {
    const int a = t >> 5, d = t & 31;
    const float* nq = nn_Q + (size_t)a * HDIM * HD + d;
    float acc = 0.f;
    for (int h = 0; h < HDIM; ++h) acc += hs[h] * nq[(size_t)h * HD];
    Qs[a][d] = acc * 0.17677669529663687f;
  }
  __syncthreads();
  for (int k = t; k < NKK; k += 256) {
    const bool mk = mbyte ? (mb[mrow + k] != 0) : (mi[mrow + k] != 0);
#pragma unroll
    for (int a = 0; a < NHEAD; ++a) {
      const float4* kr4 = reinterpret_cast<const float4*>(
          Kt + (((size_t)a * NPP + p) * NKK + k) * HD);
      float s = 0.f;
#pragma unroll
      for (int d4 = 0; d4 < HD / 4; ++d4) {
        const float4 u = kr4[d4];
        s += Qs[a][4 * d4] * u.x + Qs[a][4 * d4 + 1] * u.y
           + Qs[a][4 * d4 + 2] * u.z + Qs[a][4 * d4 + 3] * u.w;
      }
      Sb[a][k] = mk ? -INFINITY : s;
    }
  }
  __syncthreads();
  for (int aa = 0; aa < 2; ++aa) {
    const int a = wave * 2 + aa;
    float m = -INFINITY;
    for (int k = lane; k < NKK; k += 64) m = fmaxf(m, Sb[a][k]);
#pragma unroll
    for (int off = 32; off > 0; off >>= 1) m = fmaxf(m, __shfl_xor(m, off, 64));
    float ssum = 0.f;
    for (int k = lane; k < NKK; k += 64) {
      const float e = expf(Sb[a][k] - m);
      Sb[a][k] = e; ssum += e;
    }
#pragma unroll
    for (int off = 32; off > 0; off >>= 1) ssum += __shfl_xor(ssum, off, 64);
    const float inv = 1.f / ssum;
    for (int k = lane; k < NKK; k += 64) Sb[a][k] *= inv;
  }
  __syncthreads();
  {
    const int a = t >> 5, d = t & 31;
    const float* vb = Vt + ((size_t)a * NPP + p) * NKK * HD + d;
    float acc = 0.f;
    for (int k = 0; k < NKK; ++k) acc += Sb[a][k] * vb[(size_t)k * HD];
    xs[a * HD + d] = acc;
  }
  __syncthreads();
  {
    float acc = 0.f;
    for (int i = 0; i < HDIM; ++i) acc += xs[i] * nn_O[(size_t)i * HDIM + t];
    qs[t] = acc + nn_B[t];
  }
  __syncthreads();
  for (int k = t; k < NKK; k += 256) {
    float vfv[VDIM];
#pragma unroll
    for (int v = 0; v < VDIM; ++v)
      vfv[v] = varfeat[((size_t)p * VDIM + v) * NKK + k];
    const float4* xp4 = reinterpret_cast<const float4*>(
        X + ((size_t)p * NKK + k) * HDIM);
    float acc = 0.f;
    for (int h4 = 0; h4 < HDIM / 4; ++h4) {
      const float4 ux = xp4[h4];
      const float xv[4] = {ux.x, ux.y, ux.z, ux.w};
#pragma unroll
      for (int j = 0; j < 4; ++j) {
        const int h = 4 * h4 + j;
        float base = xv[j] + qs[h];
        const float4 a0 = *reinterpret_cast<const float4*>(&As2[h][0]);
        const float4 a1 = *reinterpret_cast<const float4*>(&As2[h][4]);
        base += vfv[0] * a0.x + vfv[1] * a0.y + vfv[2] * a0.z + vfv[3] * a0.w
              + vfv[4] * a1.x + vfv[5] * a1.y + vfv[6] * a1.z + vfv[7] * a1.w;
        acc += tanhf(base) * Ws[h];
      }
    }
    lsb[k] = acc;
  }
  __syncthreads();
  for (int k = t; k < NKK; k += 256) {
    const bool mk = mbyte ? (mb[mrow + k] != 0) : (mi[mrow + k] != 0);
    lsb[k] = mk ? -INFINITY : tanhf(lsb[k]) * 10.0f;
  }
  __syncthreads();
  if (wave == 0) {
    float m = -INFINITY;
    for (int k = lane; k < NKK; k += 64) m = fmaxf(m, lsb[k]);
#pragma unroll
    for (int off = 32; off > 0; off >>= 1) m = fmaxf(m, __shfl_xor(m, off, 64));
    float s = 0.f;
    for (int k = lane; k < NKK; k += 64) s += expf(lsb[k] - m);
#pragma unroll
    for (int off = 32; off > 0; off >>= 1) s += __shfl_xor(s, off, 64);
    if (lane == 0) out_p[p * NRR + r] = -logf(s);
  }
}

// ===========================================================================
extern "C" void kernel_launch(void* const* d_in, const int* in_sizes, int n_in,
                              void* d_out, int out_size, void* d_ws, size_t ws_size,
                              hipStream_t stream)
{
  const float* X       = (const float*)d_in[0];
  const float* Kt      = (const float*)d_in[1];
  const float* Vt      = (const float*)d_in[2];
  const float* query   = (const float*)d_in[3];
  const float* state1  = (const float*)d_in[4];
  const float* state2  = (const float*)d_in[5];
  const float* varfeat = (const float*)d_in[6];
  const void*  maskp   = d_in[7];
  const float* nn_Q    = (const float*)d_in[8];
  const float* nn_O    = (const float*)d_in[9];
  const float* nn_A    = (const float*)d_in[10];
  const float* nn_B    = (const float*)d_in[11];
  const float* nn_W    = (const float*)d_in[12];
  const float* W_ih    = (const float*)d_in[13];
  const float* W_hh    = (const float*)d_in[14];
  const float* b_ih    = (const float*)d_in[15];
  const float* b_hh    = (const float*)d_in[16];

  float* out   = (float*)d_out;
  float* out_h = out;
  float* out_c = out + (size_t)BTOT * HDIM;
  float* out_p = out + (size_t)2 * BTOT * HDIM;

  const size_t flag_bytes = 256;                               // aligned pad
  const size_t qm8_bytes  = (size_t)NHEAD * BTOT * HDIM * 4;   // 4 MB
  const size_t part_bytes = (size_t)BTOT * 32 * 4;             // 64 KB each
  const size_t need = flag_bytes + qm8_bytes + 2 * part_bytes; // ~4.2 MB

  if (ws_size >= need) {
    int*   flagp = (int*)d_ws;
    float* qmw  = (float*)((char*)d_ws + flag_bytes);
    float* pmax = (float*)((char*)d_ws + flag_bytes + qm8_bytes);
    float* psum = (float*)((char*)d_ws + flag_bytes + qm8_bytes + part_bytes);

    hipLaunchKernelGGL(k_lstm3, dim3(32, 16), dim3(256), 0, stream,
                       query, state1, state2, W_ih, W_hh, b_ih, b_hh,
                       (const unsigned char*)maskp, flagp, out_h, out_c);
    hipLaunchKernelGGL(k_attn9, dim3(NPP * NHEAD * 2), dim3(512), 0, stream,
                       Kt, Vt, nn_Q, nn_O, maskp, flagp, out_h, qmw);
    hipLaunchKernelGGL(k_logits6, dim3(NPP * 32), dim3(256), 0, stream,
                       X, varfeat, nn_A, nn_B, nn_W, qmw, flagp, maskp,
                       pmax, psum);
    hipLaunchKernelGGL(k_choose2, dim3(BTOT), dim3(64), 0, stream,
                       pmax, psum, out_p);
  } else {
    hipLaunchKernelGGL(k_lstm3, dim3(32, 16), dim3(256), 0, stream,
                       query, state1, state2, W_ih, W_hh, b_ih, b_hh,
                       (const unsigned char*)maskp, nullptr, out_h, out_c);
    hipLaunchKernelGGL(k_fused, dim3(NPP * NRR), dim3(256), 0, stream,
                       X, Kt, Vt, varfeat, maskp,
                       nn_Q, nn_O, nn_A, nn_B, nn_W,
                       out_h, out_p);
  }
}

// Round 4
// 227.136 us; speedup vs baseline: 1.0372x; 1.0220x over previous
//
#include <hip/hip_runtime.h>

// Problem constants (from reference) — ALL TENSORS ARE FLOAT32.
#define NPP   64
#define NRR   8
#define NKK   500
#define HDIM  256
#define NHEAD 8
#define VDIM  8
#define HD    32
#define BTOT  512   // NPP*NRR

// ---- fast transcendentals (hardware v_exp_f32 / v_rcp_f32) ----
__device__ __forceinline__ float fast_tanh(float x) {
  const float e = __expf(2.f * x);
  return 1.f - 2.f * __builtin_amdgcn_rcpf(e + 1.f);
}
__device__ __forceinline__ float fast_sig(float x) {
  return __builtin_amdgcn_rcpf(1.f + __expf(-x));
}

// ===========================================================================
// Kernel 1: LSTM cell GEMM.  C[1024 gate-rows][512 batch].
// Tile 32 gate-rows x 64 batch, 128 thr, 4x4/thread via ds_read_b128
// (rows padded to 36/68 floats: 16B-aligned, low-conflict).
// Async staging: next K-tile's global loads issued into regs BEFORE the
// compute loop, written to LDS after the barrier (T14 split).
// Grid 32 x 8 = 256 blocks.  Block (0,0) probes mask dtype into ws flag.
// ===========================================================================
__global__ __launch_bounds__(128) void k_lstm5(
    const float* __restrict__ query, const float* __restrict__ state1,
    const float* __restrict__ state2,
    const float* __restrict__ W_ih, const float* __restrict__ W_hh,
    const float* __restrict__ b_ih, const float* __restrict__ b_hh,
    const unsigned char* __restrict__ maskb, int* __restrict__ flagp,
    float* __restrict__ out_h, float* __restrict__ out_c)
{
  __shared__ float Wt[32][36];   // [k][gate-row]   4.6 KB
  __shared__ float At[32][68];   // [k][batch-col]  8.7 KB
  __shared__ float gt[32][68];   // gate exchange   8.7 KB

  const int t  = threadIdx.x;    // 128
  const int hb = blockIdx.x;     // 32 tiles of 8 h (x4 gate parts)
  const int bb = blockIdx.y;     // 8 batch tiles of 64

  if (flagp != nullptr && hb == 0 && bb == 0) {
    __shared__ int f;
    if (t == 0) f = 0;
    __syncthreads();
    int any = 0;
    for (int j = t; j < 2048; j += 128) any |= maskb[2 * j + 1];
    if (any) atomicOr(&f, 1);
    __syncthreads();
    if (t == 0) *flagp = f;
  }

  const int tr = t >> 4;                 // 0..7   -> gate-rows tr*4..+3
  const int tc = t & 15;                 // 0..15  -> batch    tc*4..+3

  // staging mapping: 128 threads cover Wt (1024 f) + At (2048 f)
  const int grow = t >> 2;               // 0..31 local gate-row
  const int kseg = t & 3;                // k-quarter (8 floats)
  const int wgrow = (grow >> 3) * HDIM + hb * 8 + (grow & 7);
  const int agrow0 = bb * 64 + grow;     // batch rows grow, grow+32
  const int agrow1 = agrow0 + 32;

  float4 wr0, wr1, ar0, ar1, ar2, ar3;

#define LSTM_ISSUE(K0)                                                        \
  {                                                                           \
    const int k0_ = (K0);                                                     \
    const float* wsrc = (k0_ < 256)                                           \
        ? (W_ih + (size_t)wgrow * HDIM + k0_)                                 \
        : (W_hh + (size_t)wgrow * HDIM + (k0_ - 256));                        \
    wr0 = *reinterpret_cast<const float4*>(wsrc + kseg * 8);                  \
    wr1 = *reinterpret_cast<const float4*>(wsrc + kseg * 8 + 4);              \
    const float* asrc0 = (k0_ < 256)                                          \
        ? (query  + (size_t)agrow0 * HDIM + k0_)                              \
        : (state1 + (size_t)agrow0 * HDIM + (k0_ - 256));                     \
    ar0 = *reinterpret_cast<const float4*>(asrc0 + kseg * 8);                 \
    ar1 = *reinterpret_cast<const float4*>(asrc0 + kseg * 8 + 4);             \
    const float* asrc1 = (k0_ < 256)                                          \
        ? (query  + (size_t)agrow1 * HDIM + k0_)                              \
        : (state1 + (size_t)agrow1 * HDIM + (k0_ - 256));                     \
    ar2 = *reinterpret_cast<const float4*>(asrc1 + kseg * 8);                 \
    ar3 = *reinterpret_cast<const float4*>(asrc1 + kseg * 8 + 4);             \
  }

#define LSTM_WRITE()                                                          \
  {                                                                           \
    const float w0[4] = {wr0.x, wr0.y, wr0.z, wr0.w};                         \
    const float w1[4] = {wr1.x, wr1.y, wr1.z, wr1.w};                         \
    const float a0[4] = {ar0.x, ar0.y, ar0.z, ar0.w};                         \
    const float a1[4] = {ar1.x, ar1.y, ar1.z, ar1.w};                         \
    const float a2[4] = {ar2.x, ar2.y, ar2.z, ar2.w};                         \
    const float a3[4] = {ar3.x, ar3.y, ar3.z, ar3.w};                         \
    _Pragma("unroll")                                                         \
    for (int i = 0; i < 4; ++i) {                                             \
      Wt[kseg * 8 + i][grow]     = w0[i];                                     \
      Wt[kseg * 8 + 4 + i][grow] = w1[i];                                     \
      At[kseg * 8 + i][grow]     = a0[i];                                     \
      At[kseg * 8 + 4 + i][grow] = a1[i];                                     \
      At[kseg * 8 + i][grow + 32]     = a2[i];                                \
      At[kseg * 8 + 4 + i][grow + 32] = a3[i];                                \
    }                                                                         \
  }

  float acc[4][4];
#pragma unroll
  for (int i = 0; i < 4; ++i)
#pragma unroll
    for (int j = 0; j < 4; ++j) acc[i][j] = 0.f;

  LSTM_ISSUE(0);
  LSTM_WRITE();
  __syncthreads();

  for (int k0 = 0; k0 < 512; k0 += 32) {
    const bool more = (k0 + 32) < 512;
    if (more) LSTM_ISSUE(k0 + 32);       // in flight during compute

#pragma unroll 8
    for (int kk = 0; kk < 32; ++kk) {
      const float4 wv = *reinterpret_cast<const float4*>(&Wt[kk][tr * 4]);
      const float4 av = *reinterpret_cast<const float4*>(&At[kk][tc * 4]);
      const float w[4] = {wv.x, wv.y, wv.z, wv.w};
      const float a[4] = {av.x, av.y, av.z, av.w};
#pragma unroll
      for (int i = 0; i < 4; ++i)
#pragma unroll
        for (int j = 0; j < 4; ++j) acc[i][j] += w[i] * a[j];
    }
    __syncthreads();
    if (more) {
      LSTM_WRITE();
      __syncthreads();
    }
  }

#pragma unroll
  for (int i = 0; i < 4; ++i) {
    float4 v;
    v.x = acc[i][0]; v.y = acc[i][1]; v.z = acc[i][2]; v.w = acc[i][3];
    *reinterpret_cast<float4*>(&gt[tr * 4 + i][tc * 4]) = v;
  }
  __syncthreads();

#pragma unroll
  for (int it = 0; it < 4; ++it) {
    const int cell = t + 128 * it;       // 512 cells = 8 h x 64 b
    const int h = cell & 7, b = cell >> 3;
    const int gh = hb * 8 + h;
    const int gb = bb * 64 + b;
    const float bi = b_ih[0 * HDIM + gh] + b_hh[0 * HDIM + gh];
    const float bf = b_ih[1 * HDIM + gh] + b_hh[1 * HDIM + gh];
    const float bg = b_ih[2 * HDIM + gh] + b_hh[2 * HDIM + gh];
    const float bo = b_ih[3 * HDIM + gh] + b_hh[3 * HDIM + gh];
    const float iv = fast_sig (gt[ 0 + h][b] + bi);
    const float fv = fast_sig (gt[ 8 + h][b] + bf);
    const float gv = fast_tanh(gt[16 + h][b] + bg);
    const float ov = fast_sig (gt[24 + h][b] + bo);
    const size_t off = (size_t)gb * HDIM + gh;
    const float c = fv * state2[off] + iv * gv;
    out_c[off] = c;
    out_h[off] = ov * fast_tanh(c);
  }
}

// ===========================================================================
// Kernel 2: attention per (p, head), 512 threads (attn8 block structure).
//  - Q-proj: ks-stride-4 float4 hs reads (conflict-free) + coalesced nn_Q.
//  - scores: K prefetched to regs at entry, Qs b128 broadcasts.
//  - V: 8 coalesced float4 per thread, issued between scores and softmax.
//  - PV: in-wave shfl reduction -> pb is 8 KB (LDS total ~35 KB, 4 blk/CU).
//  - O-proj partial -> per-head qm slab.
// ===========================================================================
__global__ __launch_bounds__(512) void k_attn10(
    const float* __restrict__ Kt, const float* __restrict__ Vt,
    const float* __restrict__ nn_Q, const float* __restrict__ nn_O,
    const void* __restrict__ maskp, const int* __restrict__ flagp,
    const float* __restrict__ out_h, float* __restrict__ qm_slabs)
{
  const int p = blockIdx.x >> 3;
  const int a = blockIdx.x & 7;
  const int t = threadIdx.x;
  const int wave = t >> 6, lane = t & 63;

  __shared__ float hs[NRR][HDIM];       // 8 KB
  __shared__ float Qs[NRR][36];         // 1.2 KB
  __shared__ float Sb[NRR][512];        // 16 KB (cols 500..511 = -inf pad)
  __shared__ float pb[8][NRR][HD];      // 8 KB per-wave PV partials
  __shared__ float xs[NRR][36];         // 1.2 KB

  // ---------- h stage + flag + K + mask prefetch -------------------------
  const float4 hv = reinterpret_cast<const float4*>(
      out_h + (size_t)p * NRR * HDIM)[t];

  const int flag = *flagp;

  const int kc = (t < NKK) ? t : (NKK - 1);
  const float4* kp4 = reinterpret_cast<const float4*>(
      Kt + (((size_t)a * NPP + p) * NKK + kc) * HD);
  float4 kreg[8];
#pragma unroll
  for (int j = 0; j < 8; ++j) kreg[j] = kp4[j];

  float maskv[NRR];
  {
    const unsigned char* mb = (const unsigned char*)maskp;
    const int* mi = (const int*)maskp;
#pragma unroll
    for (int r = 0; r < NRR; ++r) {
      const size_t mo = (size_t)(p * NRR + r) * NKK + kc;
      const bool mk = flag ? (mb[mo] != 0) : (mi[mo] != 0);
      maskv[r] = mk ? -INFINITY : 0.f;
    }
  }

  reinterpret_cast<float4*>(&hs[0][0])[t] = hv;
  __syncthreads();

  // ---------- Q-proj: wave r; lane = (d4, ks); ks stride 4 ---------------
  {
    const int r = wave;
    const int d4 = lane >> 3, ks = lane & 7;
    float qx = 0.f, qy = 0.f, qz = 0.f, qw = 0.f;
#pragma unroll
    for (int i = 0; i < 8; ++i) {
      const int hb = 32 * i + ks * 4;
      const float4 hv4 = *reinterpret_cast<const float4*>(&hs[r][hb]);
      const float hh[4] = {hv4.x, hv4.y, hv4.z, hv4.w};
      const float* nqb = nn_Q + ((size_t)a * HDIM + hb) * HD + d4 * 4;
#pragma unroll
      for (int jj = 0; jj < 4; ++jj) {
        const float4 wv = *reinterpret_cast<const float4*>(nqb + (size_t)jj * HD);
        qx += hh[jj] * wv.x; qy += hh[jj] * wv.y;
        qz += hh[jj] * wv.z; qw += hh[jj] * wv.w;
      }
    }
#pragma unroll
    for (int off = 1; off < 8; off <<= 1) {
      qx += __shfl_xor(qx, off, 64);
      qy += __shfl_xor(qy, off, 64);
      qz += __shfl_xor(qz, off, 64);
      qw += __shfl_xor(qw, off, 64);
    }
    if (ks == 0) {
      const float sc = 0.17677669529663687f;   // 1/sqrt(32)
      Qs[r][d4 * 4 + 0] = qx * sc; Qs[r][d4 * 4 + 1] = qy * sc;
      Qs[r][d4 * 4 + 2] = qz * sc; Qs[r][d4 * 4 + 3] = qw * sc;
    }
  }
  __syncthreads();

  // ---------- scores from prefetched kreg --------------------------------
#pragma unroll
  for (int r = 0; r < NRR; ++r) {
    float s = 0.f;
#pragma unroll
    for (int j = 0; j < 8; ++j) {
      const float4 q = *reinterpret_cast<const float4*>(&Qs[r][j * 4]);
      const float4 k4 = kreg[j];
      s += q.x * k4.x + q.y * k4.y + q.z * k4.z + q.w * k4.w;
    }
    Sb[r][t] = (t < NKK) ? (s + maskv[r]) : -INFINITY;
  }

  // ---------- V load issued here: in flight across softmax ---------------
  const int kg = t >> 3;                // 0..63  k-group
  const int d4p = t & 7;                // f4 dim slot
  float4 v4[8];
  {
    const float* vbase = Vt + ((size_t)a * NPP + p) * NKK * HD + d4p * 4;
#pragma unroll
    for (int j = 0; j < 8; ++j) {
      const int k = kg + 64 * j;
      v4[j] = (k < NKK)
          ? *reinterpret_cast<const float4*>(vbase + (size_t)k * HD)
          : make_float4(0.f, 0.f, 0.f, 0.f);
    }
  }
  __syncthreads();

  // ---------- softmax: wave w -> rollout w -------------------------------
  {
    const int r = wave;
    float lv[8], m = -INFINITY;
#pragma unroll
    for (int i = 0; i < 8; ++i) {
      lv[i] = Sb[r][lane + 64 * i];
      m = fmaxf(m, lv[i]);
    }
#pragma unroll
    for (int off = 32; off > 0; off >>= 1) m = fmaxf(m, __shfl_xor(m, off, 64));
    float ssum = 0.f;
#pragma unroll
    for (int i = 0; i < 8; ++i) {
      lv[i] = __expf(lv[i] - m);
      ssum += lv[i];
    }
#pragma unroll
    for (int off = 32; off > 0; off >>= 1) ssum += __shfl_xor(ssum, off, 64);
    const float inv = 1.f / ssum;
#pragma unroll
    for (int i = 0; i < 8; ++i) Sb[r][lane + 64 * i] = lv[i] * inv;
  }
  __syncthreads();

  // ---------- PV: f4 V regs x Sb broadcasts; shfl-reduce over kg ---------
  {
    float4 acc4[NRR];
#pragma unroll
    for (int r = 0; r < NRR; ++r) acc4[r] = make_float4(0.f, 0.f, 0.f, 0.f);
#pragma unroll
    for (int j = 0; j < 8; ++j) {
      const float4 v = v4[j];
#pragma unroll
      for (int r = 0; r < NRR; ++r) {
        const float s = Sb[r][kg + 64 * j];   // pad rows are exact 0
        acc4[r].x += s * v.x; acc4[r].y += s * v.y;
        acc4[r].z += s * v.z; acc4[r].w += s * v.w;
      }
    }
    // reduce over the 8 kg-slots within the wave (lane bits 3,4,5)
#pragma unroll
    for (int off = 8; off < 64; off <<= 1) {
#pragma unroll
      for (int r = 0; r < NRR; ++r) {
        acc4[r].x += __shfl_xor(acc4[r].x, off, 64);
        acc4[r].y += __shfl_xor(acc4[r].y, off, 64);
        acc4[r].z += __shfl_xor(acc4[r].z, off, 64);
        acc4[r].w += __shfl_xor(acc4[r].w, off, 64);
      }
    }
    if (lane < 8) {
#pragma unroll
      for (int r = 0; r < NRR; ++r)
        *reinterpret_cast<float4*>(&pb[wave][r][lane * 4]) = acc4[r];
    }
  }
  __syncthreads();

  if (t < 256) {
    const int r = t >> 5, d = t & 31;
    float s = 0.f;
#pragma unroll
    for (int w = 0; w < 8; ++w) s += pb[w][r][d];
    xs[r][d] = s;
  }
  __syncthreads();

  // ---------- O-proj partial -> per-head slab ----------------------------
  {
    const int j = t & 255, rr = t >> 8;   // rr: row-group {0..3} or {4..7}
    float a0 = 0.f, a1 = 0.f, a2 = 0.f, a3 = 0.f;
#pragma unroll
    for (int d4 = 0; d4 < 8; ++d4) {
      const float4 x0 = *reinterpret_cast<const float4*>(&xs[rr * 4 + 0][d4 * 4]);
      const float4 x1 = *reinterpret_cast<const float4*>(&xs[rr * 4 + 1][d4 * 4]);
      const float4 x2 = *reinterpret_cast<const float4*>(&xs[rr * 4 + 2][d4 * 4]);
      const float4 x3 = *reinterpret_cast<const float4*>(&xs[rr * 4 + 3][d4 * 4]);
      const float c0[4] = {x0.x, x0.y, x0.z, x0.w};
      const float c1[4] = {x1.x, x1.y, x1.z, x1.w};
      const float c2[4] = {x2.x, x2.y, x2.z, x2.w};
      const float c3[4] = {x3.x, x3.y, x3.z, x3.w};
#pragma unroll
      for (int dd = 0; dd < 4; ++dd) {
        const float w = nn_O[((size_t)(a * HD + d4 * 4 + dd)) * HDIM + j];
        a0 += c0[dd] * w; a1 += c1[dd] * w;
        a2 += c2[dd] * w; a3 += c3[dd] * w;
      }
    }
    float* slab = qm_slabs + (size_t)a * BTOT * HDIM;
    slab[(size_t)(p * NRR + rr * 4 + 0) * HDIM + j] = a0;
    slab[(size_t)(p * NRR + rr * 4 + 1) * HDIM + j] = a1;
    slab[(size_t)(p * NRR + rr * 4 + 2) * HDIM + j] = a2;
    slab[(size_t)(p * NRR + rr * 4 + 3) * HDIM + j] = a3;
  }
}

// ===========================================================================
// Kernel 3: qbg[512][256] = sum_a qm_slab[a] + nn_B.  Grid 128 x 256 thr,
// one float4 per thread, fully coalesced.  ~4.6 MB read, 0.5 MB write.
// ===========================================================================
__global__ __launch_bounds__(256) void k_qsum(
    const float* __restrict__ qm_slabs, const float* __restrict__ nn_B,
    float* __restrict__ qbg)
{
  const int idx = blockIdx.x * 256 + threadIdx.x;   // 32768 f4 slots
  const int row = idx >> 6, h4 = idx & 63;
  float4 acc = *reinterpret_cast<const float4*>(nn_B + h4 * 4);
#pragma unroll
  for (int a = 0; a < NHEAD; ++a) {
    const float4 q = *reinterpret_cast<const float4*>(
        qm_slabs + (size_t)a * BTOT * HDIM + (size_t)row * HDIM + h4 * 4);
    acc.x += q.x; acc.y += q.y; acc.z += q.z; acc.w += q.w;
  }
  *reinterpret_cast<float4*>(qbg + (size_t)row * HDIM + h4 * 4) = acc;
}

// ===========================================================================
// Kernel 4: additive logits + per-(row, kt) softmax partials.
// Grid 64 x 32.  Wave owns 4 k; lane owns 4 h.  q rows read directly from
// qbg (pre-summed) — no LDS, no staging barrier.
// Emits (max_l, sum exp(l-10)) — no ls materialized.
// ===========================================================================
__global__ __launch_bounds__(256) void k_logits7(
    const float* __restrict__ X, const float* __restrict__ varfeat,
    const float* __restrict__ nn_A, const float* __restrict__ nn_W,
    const float* __restrict__ qbg,
    const int* __restrict__ flagp, const void* __restrict__ maskp,
    float* __restrict__ pmax, float* __restrict__ psum)
{
  const int p  = blockIdx.x >> 5;
  const int kt = blockIdx.x & 31;
  const int t = threadIdx.x;
  const int wave = t >> 6, lane = t & 63;
  const int h0 = lane * 4;

  __shared__ float red[4][NRR][2];      // per-wave (max, sum) partials

  const unsigned char* mb = (const unsigned char*)maskp;
  const int* mi = (const int*)maskp;
  const int flag = *flagp;
  const bool mbyte = (flag != 0);

  const float4 w4 = *reinterpret_cast<const float4*>(nn_W + h0);
  float4 a4r[VDIM];
#pragma unroll
  for (int v = 0; v < VDIM; ++v)
    a4r[v] = *reinterpret_cast<const float4*>(nn_A + (size_t)v * HDIM + h0);
  float4 q4r[NRR];
#pragma unroll
  for (int r = 0; r < NRR; ++r)
    q4r[r] = *reinterpret_cast<const float4*>(
        qbg + (size_t)(p * NRR + r) * HDIM + h0);

  float rmax = -INFINITY, rsum = 0.f;    // valid at lanes with (lane&7)==0

  for (int kk = 0; kk < 4; ++kk) {
    const int k = kt * 16 + wave * 4 + kk;
    if (k >= NKK) break;   // wave-uniform

    const float4 x4 = *reinterpret_cast<const float4*>(
        X + ((size_t)p * NKK + k) * HDIM + h0);
    float base0 = x4.x, base1 = x4.y, base2 = x4.z, base3 = x4.w;
#pragma unroll
    for (int v = 0; v < VDIM; ++v) {
      const float vv = varfeat[((size_t)p * VDIM + v) * NKK + k];
      base0 += vv * a4r[v].x; base1 += vv * a4r[v].y;
      base2 += vv * a4r[v].z; base3 += vv * a4r[v].w;
    }

    float acc[NRR];
#pragma unroll
    for (int r = 0; r < NRR; ++r) {
      acc[r] = fast_tanh(base0 + q4r[r].x) * w4.x
             + fast_tanh(base1 + q4r[r].y) * w4.y
             + fast_tanh(base2 + q4r[r].z) * w4.z
             + fast_tanh(base3 + q4r[r].w) * w4.w;
    }

    // multi-value wave reduction: 8 sums across 64 lanes
    float v4[4];
    {
      float sw[8];
#pragma unroll
      for (int j = 0; j < 8; ++j) sw[j] = __shfl_xor(acc[j], 32, 64);
      const bool hi = (lane & 32) != 0;
#pragma unroll
      for (int j = 0; j < 4; ++j)
        v4[j] = hi ? (acc[j + 4] + sw[j + 4]) : (acc[j] + sw[j]);
    }
    float v2[2];
    {
      float sw[4];
#pragma unroll
      for (int j = 0; j < 4; ++j) sw[j] = __shfl_xor(v4[j], 16, 64);
      const bool hi = (lane & 16) != 0;
      v2[0] = hi ? (v4[2] + sw[2]) : (v4[0] + sw[0]);
      v2[1] = hi ? (v4[3] + sw[3]) : (v4[1] + sw[1]);
    }
    float w;
    {
      const float s0 = __shfl_xor(v2[0], 8, 64);
      const float s1 = __shfl_xor(v2[1], 8, 64);
      w = ((lane & 8) != 0) ? (v2[1] + s1) : (v2[0] + s0);
    }
    w += __shfl_xor(w, 4, 64);
    w += __shfl_xor(w, 2, 64);
    w += __shfl_xor(w, 1, 64);

    if ((lane & 7) == 0) {
      const int r = lane >> 3;
      const size_t mrow = (size_t)(p * NRR + r) * NKK + k;
      const bool mk = mbyte ? (mb[mrow] != 0) : (mi[mrow] != 0);
      const float l = mk ? -INFINITY : fast_tanh(w) * 10.0f;
      rmax = fmaxf(rmax, l);
      rsum += __expf(l - 10.f);          // exp(-inf) = 0 for masked
    }
  }

  if ((lane & 7) == 0) {
    red[wave][lane >> 3][0] = rmax;
    red[wave][lane >> 3][1] = rsum;
  }
  __syncthreads();
  if (t < NRR) {
    float m = red[0][t][0], s = red[0][t][1];
#pragma unroll
    for (int w = 1; w < 4; ++w) {
      m = fmaxf(m, red[w][t][0]);
      s += red[w][t][1];
    }
    pmax[(size_t)(p * NRR + t) * 32 + kt] = m;
    psum[(size_t)(p * NRR + t) * 32 + kt] = s;
  }
}

// ===========================================================================
// Kernel 5: choose.  One wave per batch row; reduce the 32 kt-partials.
// chosen_p = m - LSE = m - 10 - log(sum exp(l-10)).
// ===========================================================================
__global__ __launch_bounds__(64) void k_choose2(
    const float* __restrict__ pmax, const float* __restrict__ psum,
    float* __restrict__ out_p)
{
  const int b = blockIdx.x;
  const int lane = threadIdx.x;
  float m = (lane < 32) ? pmax[(size_t)b * 32 + lane] : -INFINITY;
  float s = (lane < 32) ? psum[(size_t)b * 32 + lane] : 0.f;
#pragma unroll
  for (int off = 16; off > 0; off >>= 1) {
    m = fmaxf(m, __shfl_xor(m, off, 64));
    s += __shfl_xor(s, off, 64);
  }
  if (lane == 0) out_p[b] = m - 10.f - logf(s);
}

// ===========================================================================
// Fallback (ws too small): fused kernel — known-correct.
// ===========================================================================
__global__ __launch_bounds__(256) void k_fused(
    const float* __restrict__ X, const float* __restrict__ Kt,
    const float* __restrict__ Vt, const float* __restrict__ varfeat,
    const void* __restrict__ maskp,
    const float* __restrict__ nn_Q, const float* __restrict__ nn_O,
    const float* __restrict__ nn_A, const float* __restrict__ nn_B,
    const float* __restrict__ nn_W,
    const float* __restrict__ out_h, float* __restrict__ out_p)
{
  const int p = blockIdx.x >> 3;
  const int r = blockIdx.x & 7;
  const int t = threadIdx.x;
  const int wave = t >> 6, lane = t & 63;

  __shared__ float hs[HDIM];
  __shared__ float Qs[NHEAD][HD];
  __shared__ float Sb[NHEAD][NKK];
  __shared__ float xs[HDIM];
  __shared__ float qs[HDIM];
  __shared__ float As2[HDIM][VDIM];
  __shared__ float Ws[HDIM];
  __shared__ float lsb[NKK];
  __shared__ int   mask_any;

  const unsigned char* mb = (const unsigned char*)maskp;
  if (t == 0) mask_any = 0;
  __syncthreads();
  {
    int any = 0;
    for (int j = t; j < 2048; j += 256) any |= mb[2 * j + 1];
    if (any) atomicOr(&mask_any, 1);
  }
  for (int idx = t; idx < VDIM * HDIM; idx += 256)
    As2[idx & 255][idx >> 8] = nn_A[idx];
  Ws[t] = nn_W[t];
  hs[t] = out_h[(size_t)(p * NRR + r) * HDIM + t];
  __syncthreads();
  const bool mbyte = (mask_any != 0);
  const int* mi = (const int*)maskp;
  const size_t mrow = (size_t)(p * NRR + r) * NKK;
  {
    const int a = t >> 5, d = t & 31;
    const float* nq = nn_Q + (size_t)a * HDIM * HD + d;
    float acc = 0.f;
    for (int h = 0; h < HDIM; ++h) acc += hs[h] * nq[(size_t)h * HD];
    Qs[a][d] = acc * 0.17677669529663687f;
  }
  __syncthreads();
  for (int k = t; k < NKK; k += 256) {
    const bool mk = mbyte ? (mb[mrow + k] != 0) : (mi[mrow + k] != 0);
#pragma unroll
    for (int a = 0; a < NHEAD; ++a) {
      const float4* kr4 = reinterpret_cast<const float4*>(
          Kt + (((size_t)a * NPP + p) * NKK + k) * HD);
      float s = 0.f;
#pragma unroll
      for (int d4 = 0; d4 < HD / 4; ++d4) {
        const float4 u = kr4[d4];
        s += Qs[a][4 * d4] * u.x + Qs[a][4 * d4 + 1] * u.y
           + Qs[a][4 * d4 + 2] * u.z + Qs[a][4 * d4 + 3] * u.w;
      }
      Sb[a][k] = mk ? -INFINITY : s;
    }
  }
  __syncthreads();
  for (int aa = 0; aa < 2; ++aa) {
    const int a = wave * 2 + aa;
    float m = -INFINITY;
    for (int k = lane; k < NKK; k += 64) m = fmaxf(m, Sb[a][k]);
#pragma unroll
    for (int off = 32; off > 0; off >>= 1) m = fmaxf(m, __shfl_xor(m, off, 64));
    float ssum = 0.f;
    for (int k = lane; k < NKK; k += 64) {
      const float e = expf(Sb[a][k] - m);
      Sb[a][k] = e; ssum += e;
    }
#pragma unroll
    for (int off = 32; off > 0; off >>= 1) ssum += __shfl_xor(ssum, off, 64);
    const float inv = 1.f / ssum;
    for (int k = lane; k < NKK; k += 64) Sb[a][k] *= inv;
  }
  __syncthreads();
  {
    const int a = t >> 5, d = t & 31;
    const float* vb = Vt + ((size_t)a * NPP + p) * NKK * HD + d;
    float acc = 0.f;
    for (int k = 0; k < NKK; ++k) acc += Sb[a][k] * vb[(size_t)k * HD];
    xs[a * HD + d] = acc;
  }
  __syncthreads();
  {
    float acc = 0.f;
    for (int i = 0; i < HDIM; ++i) acc += xs[i] * nn_O[(size_t)i * HDIM + t];
    qs[t] = acc + nn_B[t];
  }
  __syncthreads();
  for (int k = t; k < NKK; k += 256) {
    float vfv[VDIM];
#pragma unroll
    for (int v = 0; v < VDIM; ++v)
      vfv[v] = varfeat[((size_t)p * VDIM + v) * NKK + k];
    const float4* xp4 = reinterpret_cast<const float4*>(
        X + ((size_t)p * NKK + k) * HDIM);
    float acc = 0.f;
    for (int h4 = 0; h4 < HDIM / 4; ++h4) {
      const float4 ux = xp4[h4];
      const float xv[4] = {ux.x, ux.y, ux.z, ux.w};
#pragma unroll
      for (int j = 0; j < 4; ++j) {
        const int h = 4 * h4 + j;
        float base = xv[j] + qs[h];
        const float4 a0 = *reinterpret_cast<const float4*>(&As2[h][0]);
        const float4 a1 = *reinterpret_cast<const float4*>(&As2[h][4]);
        base += vfv[0] * a0.x + vfv[1] * a0.y + vfv[2] * a0.z + vfv[3] * a0.w
              + vfv[4] * a1.x + vfv[5] * a1.y + vfv[6] * a1.z + vfv[7] * a1.w;
        acc += tanhf(base) * Ws[h];
      }
    }
    lsb[k] = acc;
  }
  __syncthreads();
  for (int k = t; k < NKK; k += 256) {
    const bool mk = mbyte ? (mb[mrow + k] != 0) : (mi[mrow + k] != 0);
    lsb[k] = mk ? -INFINITY : tanhf(lsb[k]) * 10.0f;
  }
  __syncthreads();
  if (wave == 0) {
    float m = -INFINITY;
    for (int k = lane; k < NKK; k += 64) m = fmaxf(m, lsb[k]);
#pragma unroll
    for (int off = 32; off > 0; off >>= 1) m = fmaxf(m, __shfl_xor(m, off, 64));
    float s = 0.f;
    for (int k = lane; k < NKK; k += 64) s += expf(lsb[k] - m);
#pragma unroll
    for (int off = 32; off > 0; off >>= 1) s += __shfl_xor(s, off, 64);
    if (lane == 0) out_p[p * NRR + r] = -logf(s);
  }
}

// ===========================================================================
extern "C" void kernel_launch(void* const* d_in, const int* in_sizes, int n_in,
                              void* d_out, int out_size, void* d_ws, size_t ws_size,
                              hipStream_t stream)
{
  const float* X       = (const float*)d_in[0];
  const float* Kt      = (const float*)d_in[1];
  const float* Vt      = (const float*)d_in[2];
  const float* query   = (const float*)d_in[3];
  const float* state1  = (const float*)d_in[4];
  const float* state2  = (const float*)d_in[5];
  const float* varfeat = (const float*)d_in[6];
  const void*  maskp   = d_in[7];
  const float* nn_Q    = (const float*)d_in[8];
  const float* nn_O    = (const float*)d_in[9];
  const float* nn_A    = (const float*)d_in[10];
  const float* nn_B    = (const float*)d_in[11];
  const float* nn_W    = (const float*)d_in[12];
  const float* W_ih    = (const float*)d_in[13];
  const float* W_hh    = (const float*)d_in[14];
  const float* b_ih    = (const float*)d_in[15];
  const float* b_hh    = (const float*)d_in[16];

  float* out   = (float*)d_out;
  float* out_h = out;
  float* out_c = out + (size_t)BTOT * HDIM;
  float* out_p = out + (size_t)2 * BTOT * HDIM;

  const size_t flag_bytes = 256;                               // aligned pad
  const size_t qm8_bytes  = (size_t)NHEAD * BTOT * HDIM * 4;   // 4 MB
  const size_t qbg_bytes  = (size_t)BTOT * HDIM * 4;           // 512 KB
  const size_t part_bytes = (size_t)BTOT * 32 * 4;             // 64 KB each
  const size_t need = flag_bytes + qm8_bytes + qbg_bytes + 2 * part_bytes;

  if (ws_size >= need) {
    int*   flagp = (int*)d_ws;
    float* qmw  = (float*)((char*)d_ws + flag_bytes);
    float* qbg  = (float*)((char*)d_ws + flag_bytes + qm8_bytes);
    float* pmax = (float*)((char*)d_ws + flag_bytes + qm8_bytes + qbg_bytes);
    float* psum = (float*)((char*)d_ws + flag_bytes + qm8_bytes + qbg_bytes
                           + part_bytes);

    hipLaunchKernelGGL(k_lstm5, dim3(32, 8), dim3(128), 0, stream,
                       query, state1, state2, W_ih, W_hh, b_ih, b_hh,
                       (const unsigned char*)maskp, flagp, out_h, out_c);
    hipLaunchKernelGGL(k_attn10, dim3(NPP * NHEAD), dim3(512), 0, stream,
                       Kt, Vt, nn_Q, nn_O, maskp, flagp, out_h, qmw);
    hipLaunchKernelGGL(k_qsum, dim3(128), dim3(256), 0, stream,
                       qmw, nn_B, qbg);
    hipLaunchKernelGGL(k_logits7, dim3(NPP * 32), dim3(256), 0, stream,
                       X, varfeat, nn_A, nn_W, qbg, flagp, maskp,
                       pmax, psum);
    hipLaunchKernelGGL(k_choose2, dim3(BTOT), dim3(64), 0, stream,
                       pmax, psum, out_p);
  } else {
    hipLaunchKernelGGL(k_lstm5, dim3(32, 8), dim3(128), 0, stream,
                       query, state1, state2, W_ih, W_hh, b_ih, b_hh,
                       (const unsigned char*)maskp, nullptr, out_h, out_c);
    hipLaunchKernelGGL(k_fused, dim3(NPP * NRR), dim3(256), 0, stream,
                       X, Kt, Vt, varfeat, maskp,
                       nn_Q, nn_O, nn_A, nn_B, nn_W,
                       out_h, out_p);
  }
}